// Round 13
// baseline (288.714 us; speedup 1.0000x reference)
//
#include <hip/hip_runtime.h>

#define N_NODES 32000
#define NPG     2000
#define NGRAPH  16
#define K_ASSIGN 1600
#define KPG     100
#define D_FEAT  128
#define N_EDGES 512000

typedef float f32x4 __attribute__((ext_vector_type(4)));
typedef __bf16 bf16x8 __attribute__((ext_vector_type(8)));

union FragU { unsigned u[4]; bf16x8 v; };

__device__ __forceinline__ float frelu(float v) { return fmaxf(v, 0.0f); }

__device__ __forceinline__ unsigned short f2bf(float f) {
  unsigned u = __float_as_uint(f);
  u += 0x7FFFu + ((u >> 16) & 1u);
  return (unsigned short)(u >> 16);
}
__device__ __forceinline__ float bfLO(unsigned v) { return __uint_as_float(v << 16); }
__device__ __forceinline__ float bfHI(unsigned v) { return __uint_as_float(v & 0xFFFF0000u); }

// ---------------------------------------------------------------------------
// prep_all: weight transposes (f32->bf16 [C][R]) + h->bf16 + edge histogram.
// ---------------------------------------------------------------------------
__global__ __launch_bounds__(256) void prep_all(
    const float* __restrict__ W1f, const float* __restrict__ W2f,
    const float* __restrict__ W1p, const float* __restrict__ W2p,
    unsigned short* __restrict__ o1, unsigned short* __restrict__ o2,
    unsigned short* __restrict__ o3, unsigned short* __restrict__ o4,
    const float* __restrict__ h, unsigned short* __restrict__ h_bf,
    const int* __restrict__ dst, int* __restrict__ cnt) {
  __shared__ float tile[32][33];
  int b = blockIdx.x;
  int t = threadIdx.x;
  if (b >= 6732) {  // edge histogram
    int e = (b - 6732) * 256 + t;
    if (e < N_EDGES) atomicAdd(&cnt[dst[e]], 1);
    return;
  }
  if (b >= 2732) {  // h -> bf16
    int i = (b - 2732) * 256 + t;  // float4 index
    float4 v = ((const float4*)h)[i];
    ushort4 o;
    o.x = f2bf(v.x); o.y = f2bf(v.y); o.z = f2bf(v.z); o.w = f2bf(v.w);
    ((ushort4*)h_bf)[i] = o;
    return;
  }
  const float* in;
  unsigned short* out;
  int R, C, rb;
  if (b < 16)       { in = W1f; out = o1; R = 128;  C = 128;  rb = b; }
  else if (b < 32)  { in = W2f; out = o2; R = 128;  C = 128;  rb = b - 16; }
  else if (b < 232) { in = W1p; out = o3; R = 128;  C = 1600; rb = b - 32; }
  else              { in = W2p; out = o4; R = 1600; C = 1600; rb = b - 232; }
  int ct = C >> 5;
  int bc = rb % ct, br = rb / ct;
  int r0 = br * 32, c0 = bc * 32;
#pragma unroll
  for (int i = 0; i < 4; i++) {
    int r = (t >> 5) + i * 8, c = t & 31;
    tile[r][c] = in[(size_t)(r0 + r) * C + c0 + c];
  }
  __syncthreads();
#pragma unroll
  for (int i = 0; i < 4; i++) {
    int c = (t >> 5) + i * 8, r = t & 31;
    out[(size_t)(c0 + c) * R + r0 + r] = f2bf(tile[r][c]);
  }
}

// ---------------------------------------------------------------------------
// CSR scan: 1024 threads, 32 counts each (1000 active).
// ---------------------------------------------------------------------------
__global__ __launch_bounds__(1024) void scan_counts(
    const int* __restrict__ cnt, int* __restrict__ rowstart) {
  __shared__ int sums[1024];
  int t = threadIdx.x;
  int base = t * 32;
  int s = 0;
  if (t < 1000)
    for (int i = 0; i < 32; i++) s += cnt[base + i];
  sums[t] = s;
  __syncthreads();
  for (int off = 1; off < 1024; off <<= 1) {
    int v = (t >= off) ? sums[t - off] : 0;
    __syncthreads();
    sums[t] += v;
    __syncthreads();
  }
  if (t < 1000) {
    int run = (t == 0) ? 0 : sums[t - 1];
    for (int i = 0; i < 32; i++) {
      rowstart[base + i] = run;
      run += cnt[base + i];
    }
  }
  if (t == 999) rowstart[32000] = sums[999];
}

__global__ __launch_bounds__(256) void edge_fill(
    const int* __restrict__ src, const int* __restrict__ dst,
    const int* __restrict__ rowstart, int* __restrict__ cursor,
    int* __restrict__ bucket) {
  int e = blockIdx.x * 256 + threadIdx.x;
  if (e < N_EDGES) {
    int d = dst[e];
    int pos = atomicAdd(&cursor[d], 1);
    bucket[rowstart[d] + pos] = src[e];
  }
}

// ---------------------------------------------------------------------------
// Gather aggregation + compute_x: x_bf[n] = bf16(h_bf[n] + mean h_bf[src]).
// Standalone, XCD-chunked swizzle, high occupancy (r9/r12 lesson: latency-
// bound gathers must not carry MFMA-kernel footprints or lose the swizzle).
// ---------------------------------------------------------------------------
__global__ __launch_bounds__(256) void gin_gather(
    const int* __restrict__ rowstart, const int* __restrict__ bucket,
    const unsigned short* __restrict__ h_bf, unsigned short* __restrict__ x_bf) {
  int bid = (int)(blockIdx.x & 7) * 1000 + (int)(blockIdx.x >> 3);
  int n = bid * 4 + (threadIdx.x >> 6);
  int lane = threadIdx.x & 63;
  int rs = rowstart[n], re = rowstart[n + 1];
  int deg = re - rs;
  const unsigned* hb = (const unsigned*)h_bf;
  unsigned hv = hb[(size_t)n * 64 + lane];
  float ax = 0.f, ay = 0.f;
  for (int base = 0; base < deg; base += 64) {
    int cnt = deg - base;
    if (cnt > 64) cnt = 64;
    int myidx = (lane < cnt) ? bucket[rs + base + lane] : 0;
    int j = 0;
    for (; j + 8 <= cnt; j += 8) {
      int s0 = __shfl(myidx, j + 0), s1 = __shfl(myidx, j + 1);
      int s2 = __shfl(myidx, j + 2), s3 = __shfl(myidx, j + 3);
      int s4 = __shfl(myidx, j + 4), s5 = __shfl(myidx, j + 5);
      int s6 = __shfl(myidx, j + 6), s7 = __shfl(myidx, j + 7);
      unsigned v0 = hb[(size_t)s0 * 64 + lane];
      unsigned v1 = hb[(size_t)s1 * 64 + lane];
      unsigned v2 = hb[(size_t)s2 * 64 + lane];
      unsigned v3 = hb[(size_t)s3 * 64 + lane];
      unsigned v4 = hb[(size_t)s4 * 64 + lane];
      unsigned v5 = hb[(size_t)s5 * 64 + lane];
      unsigned v6 = hb[(size_t)s6 * 64 + lane];
      unsigned v7 = hb[(size_t)s7 * 64 + lane];
      ax += ((bfLO(v0) + bfLO(v1)) + (bfLO(v2) + bfLO(v3))) +
            ((bfLO(v4) + bfLO(v5)) + (bfLO(v6) + bfLO(v7)));
      ay += ((bfHI(v0) + bfHI(v1)) + (bfHI(v2) + bfHI(v3))) +
            ((bfHI(v4) + bfHI(v5)) + (bfHI(v6) + bfHI(v7)));
    }
    for (; j < cnt; j++) {
      int s0 = __shfl(myidx, j);
      unsigned v = hb[(size_t)s0 * 64 + lane];
      ax += bfLO(v);
      ay += bfHI(v);
    }
  }
  float invd = 1.0f / fmaxf((float)deg, 1.0f);
  unsigned o = ((unsigned)f2bf(bfHI(hv) + ay * invd) << 16) |
               f2bf(bfLO(hv) + ax * invd);
  ((unsigned*)x_bf)[(size_t)n * 64 + lane] = o;
}

// ---------------------------------------------------------------------------
// MERGED feat + assign, weights DIRECT FROM GLOBAL (L1/L2-resident):
// no weight LDS staging, no double-buffering, NO barriers in the K-loop.
// Blocks [0,256): assign+softmax (128 rows); [256,506): feat MLP (128 rows).
// LDS = 34816 B (x tile only; reduction reuses it in 2 passes).
// ---------------------------------------------------------------------------
#define FF_STR 136
#define FA_WS 136
__global__ __launch_bounds__(512) void feat_assign(
    const unsigned short* __restrict__ x_bf,
    const unsigned short* __restrict__ w1ft, const float* __restrict__ b1f,
    const unsigned short* __restrict__ w2ft, const float* __restrict__ b2f,
    unsigned short* __restrict__ feat_bf,
    const unsigned short* __restrict__ w1t, const float* __restrict__ b1p,
    const unsigned short* __restrict__ w2t, const float* __restrict__ b2p,
    unsigned short* __restrict__ assign_bf) {
  __shared__ __align__(16) unsigned char smem[34816];
  int t = threadIdx.x;
  int w = t >> 6, l = t & 63, lr = l & 15, lg = l >> 4;

  if (blockIdx.x >= 256) {
    // ---------------- feat path (barrier-free) ----------------
    unsigned short* xa = (unsigned short*)smem;
    size_t base = (size_t)(blockIdx.x - 256) * 128;
    // stage own 16-row stripe (wave-synchronous LDS: no barrier needed)
#pragma unroll
    for (int j = 0; j < 4; j++) {
      int idx = l + 64 * j;
      int r = 16 * w + (idx >> 4), u8 = (idx & 15) * 8;
      *(uint4*)&xa[r * FF_STR + u8] = *(const uint4*)(x_bf + (base + r) * 128 + u8);
    }
    int myrow = 16 * w + lr;
    bf16x8 af[4];
#pragma unroll
    for (int kc = 0; kc < 4; kc++)
      af[kc] = *(bf16x8*)&xa[myrow * FF_STR + 32 * kc + 8 * lg];

    // phase 1 (swapped): weights direct from global (w1ft = 32 KB, L1-hit)
    f32x4 p[8];
#pragma unroll
    for (int ntk = 0; ntk < 8; ntk++) {
      int c = 16 * ntk + lr;
      bf16x8 wfr[4];
#pragma unroll
      for (int kc = 0; kc < 4; kc++)
        wfr[kc] = *(const bf16x8*)(w1ft + (size_t)c * 128 + 32 * kc + 8 * lg);
      p[ntk] = (f32x4){0.f, 0.f, 0.f, 0.f};
#pragma unroll
      for (int kc = 0; kc < 4; kc++)
        p[ntk] = __builtin_amdgcn_mfma_f32_16x16x32_bf16(wfr[kc], af[kc], p[ntk], 0, 0, 0);
    }
    // x1 -> own stripe (wave-local)
#pragma unroll
    for (int ntk = 0; ntk < 8; ntk++) {
      int kk0 = 16 * ntk + 4 * lg;
      float4 b1 = *(const float4*)(b1f + kk0);
      ushort4 pk;
      pk.x = f2bf(frelu(p[ntk][0] + b1.x));
      pk.y = f2bf(frelu(p[ntk][1] + b1.y));
      pk.z = f2bf(frelu(p[ntk][2] + b1.z));
      pk.w = f2bf(frelu(p[ntk][3] + b1.w));
      *(ushort4*)&xa[myrow * FF_STR + kk0] = pk;
    }
    bf16x8 a2[4];
#pragma unroll
    for (int kc = 0; kc < 4; kc++)
      a2[kc] = *(bf16x8*)&xa[myrow * FF_STR + 32 * kc + 8 * lg];
    // phase 2 (swapped)
#pragma unroll
    for (int nt = 0; nt < 8; nt++) {
      int c = 16 * nt + lr;
      bf16x8 wfr[4];
#pragma unroll
      for (int kc = 0; kc < 4; kc++)
        wfr[kc] = *(const bf16x8*)(w2ft + (size_t)c * 128 + 32 * kc + 8 * lg);
      f32x4 q = (f32x4){0.f, 0.f, 0.f, 0.f};
#pragma unroll
      for (int kc = 0; kc < 4; kc++)
        q = __builtin_amdgcn_mfma_f32_16x16x32_bf16(wfr[kc], a2[kc], q, 0, 0, 0);
      int c0 = 16 * nt + 4 * lg;
      float4 b2 = *(const float4*)(b2f + c0);
      ushort4 pk;
      pk.x = f2bf(frelu(q[0] + b2.x));
      pk.y = f2bf(frelu(q[1] + b2.y));
      pk.z = f2bf(frelu(q[2] + b2.z));
      pk.w = f2bf(frelu(q[3] + b2.w));
      *(ushort4*)&feat_bf[(base + myrow) * 128 + c0] = pk;
    }
    return;
  }

  // ---------------- assign path (no barriers in K-loop) ----------------
  unsigned short* xt = (unsigned short*)smem;
  int g = blockIdx.x >> 4;
  int row0 = (blockIdx.x & 15) << 7;
  int n0 = g * NPG + row0;

#pragma unroll
  for (int i = 0; i < 4; i++) {
    int fi = t + 512 * i;
    int r = fi >> 4, u8 = (fi & 15) * 8;
    uint4 v = make_uint4(0, 0, 0, 0);
    if (row0 + r < NPG) v = *(const uint4*)(x_bf + (size_t)(n0 + r) * 128 + u8);
    *(uint4*)&xt[r * FA_WS + u8] = v;
  }
  __syncthreads();

  int rh = w >> 1, hh = w & 1;

  // resident x fragments: rows 32rh+16ct+lr, k = 32kc+8lg..+7
  bf16x8 af[2][4];
#pragma unroll
  for (int ct = 0; ct < 2; ct++)
#pragma unroll
    for (int kc = 0; kc < 4; kc++)
      af[ct][kc] =
          *(bf16x8*)&xt[(32 * rh + 16 * ct + lr) * FA_WS + 32 * kc + 8 * lg];
  // xt not touched again until the end-of-kernel reduction (barrier there).

  f32x4 acc[7][2];
#pragma unroll
  for (int i = 0; i < 7; i++) {
    acc[i][0] = (f32x4){0.f, 0.f, 0.f, 0.f};
    acc[i][1] = (f32x4){0.f, 0.f, 0.f, 0.f};
  }

  for (int cch = 0; cch < 25; cch++) {
    int k0 = cch * 64;
    // phase 1 (swapped): w1 fragments direct from global (w1p_t L2-resident)
    f32x4 p[2][2];
    __builtin_amdgcn_s_setprio(1);
#pragma unroll
    for (int nt2 = 0; nt2 < 2; nt2++) {
      bf16x8 wfr[4];
#pragma unroll
      for (int kc = 0; kc < 4; kc++)
        wfr[kc] = *(const bf16x8*)(
            w1t + (size_t)(k0 + 16 * (2 * hh + nt2) + lr) * 128 + 32 * kc + 8 * lg);
      p[nt2][0] = (f32x4){0.f, 0.f, 0.f, 0.f};
      p[nt2][1] = (f32x4){0.f, 0.f, 0.f, 0.f};
#pragma unroll
      for (int kc = 0; kc < 4; kc++) {
        p[nt2][0] = __builtin_amdgcn_mfma_f32_16x16x32_bf16(wfr[kc], af[0][kc],
                                                            p[nt2][0], 0, 0, 0);
        p[nt2][1] = __builtin_amdgcn_mfma_f32_16x16x32_bf16(wfr[kc], af[1][kc],
                                                            p[nt2][1], 0, 0, 0);
      }
    }
    __builtin_amdgcn_s_setprio(0);
    // bias + relu + pack to bf16 pairs
    unsigned q[2][2][2];
#pragma unroll
    for (int nt2 = 0; nt2 < 2; nt2++) {
      int kkb = k0 + 16 * (2 * hh + nt2) + 4 * lg;
      float4 b1 = *(const float4*)(b1p + kkb);
#pragma unroll
      for (int ct = 0; ct < 2; ct++) {
        float r0 = frelu(p[nt2][ct][0] + b1.x);
        float r1 = frelu(p[nt2][ct][1] + b1.y);
        float r2 = frelu(p[nt2][ct][2] + b1.z);
        float r3 = frelu(p[nt2][ct][3] + b1.w);
        q[nt2][ct][0] = ((unsigned)f2bf(r1) << 16) | f2bf(r0);
        q[nt2][ct][1] = ((unsigned)f2bf(r3) << 16) | f2bf(r2);
      }
    }
    // regroup to B-frag layout via shfl (within-wave)
    int sA = lr + 32 * (lg & 1);
    int sB = sA + 16;
    bool hi = (lg >= 2);
    FragU pa[2];
#pragma unroll
    for (int ct = 0; ct < 2; ct++) {
      unsigned a0 = (unsigned)__shfl((int)q[0][ct][0], sA, 64);
      unsigned b0 = (unsigned)__shfl((int)q[1][ct][0], sA, 64);
      unsigned a1 = (unsigned)__shfl((int)q[0][ct][1], sA, 64);
      unsigned b1u = (unsigned)__shfl((int)q[1][ct][1], sA, 64);
      unsigned a2 = (unsigned)__shfl((int)q[0][ct][0], sB, 64);
      unsigned b2u = (unsigned)__shfl((int)q[1][ct][0], sB, 64);
      unsigned a3 = (unsigned)__shfl((int)q[0][ct][1], sB, 64);
      unsigned b3u = (unsigned)__shfl((int)q[1][ct][1], sB, 64);
      pa[ct].u[0] = hi ? b0 : a0;
      pa[ct].u[1] = hi ? b1u : a1;
      pa[ct].u[2] = hi ? b2u : a2;
      pa[ct].u[3] = hi ? b3u : a3;
    }
    // phase 2 (swapped): w2 fragments direct from global (per-graph 320 KB
    // slice, L2-resident). Rows >= KPG clamped — garbage feeds only output
    // rows that are masked at the epilogue.
    __builtin_amdgcn_s_setprio(1);
#pragma unroll
    for (int ct2 = 0; ct2 < 7; ct2++) {
      int c = 16 * ct2 + lr;
      int crow = g * KPG + (c < KPG ? c : KPG - 1);
      bf16x8 wv = *(const bf16x8*)(
          w2t + (size_t)crow * K_ASSIGN + k0 + 32 * hh + 8 * lg);
      acc[ct2][0] = __builtin_amdgcn_mfma_f32_16x16x32_bf16(wv, pa[0].v,
                                                            acc[ct2][0], 0, 0, 0);
      acc[ct2][1] = __builtin_amdgcn_mfma_f32_16x16x32_bf16(wv, pa[1].v,
                                                            acc[ct2][1], 0, 0, 0);
    }
    __builtin_amdgcn_s_setprio(0);
  }

  // cross-h reduction + softmax, 2 passes over ct (fits 34816 B LDS:
  // (3*7+6)*64*4 floats = 28,608 B max index)
  float* red = (float*)smem;
#pragma unroll
  for (int ct = 0; ct < 2; ct++) {
    __syncthreads();  // previous pass reads done / xt dead
    if (hh == 1) {
#pragma unroll
      for (int ct2 = 0; ct2 < 7; ct2++)
        *(f32x4*)&red[((rh * 7 + ct2) * 64 + l) * 4] = acc[ct2][ct];
    }
    __syncthreads();
    if (hh == 0) {
#pragma unroll
      for (int ct2 = 0; ct2 < 7; ct2++)
        acc[ct2][ct] += *(f32x4*)&red[((rh * 7 + ct2) * 64 + l) * 4];

      int xrow = row0 + 32 * rh + 16 * ct + lr;
      float v[7][4];
      float m = 0.0f;  // reference max includes masked zeros
#pragma unroll
      for (int ct2 = 0; ct2 < 7; ct2++) {
        int col0 = 16 * ct2 + 4 * lg;
        if (col0 < KPG) {
          float4 b2 = *(const float4*)(b2p + g * KPG + col0);
          v[ct2][0] = frelu(acc[ct2][ct][0] + b2.x);
          v[ct2][1] = frelu(acc[ct2][ct][1] + b2.y);
          v[ct2][2] = frelu(acc[ct2][ct][2] + b2.z);
          v[ct2][3] = frelu(acc[ct2][ct][3] + b2.w);
          m = fmaxf(m, fmaxf(fmaxf(v[ct2][0], v[ct2][1]),
                             fmaxf(v[ct2][2], v[ct2][3])));
        }
      }
      m = fmaxf(m, __shfl_xor(m, 16, 64));
      m = fmaxf(m, __shfl_xor(m, 32, 64));
      float s = 0.0f;
#pragma unroll
      for (int ct2 = 0; ct2 < 7; ct2++) {
        int col0 = 16 * ct2 + 4 * lg;
        if (col0 < KPG) {
          v[ct2][0] = expf(v[ct2][0] - m);
          v[ct2][1] = expf(v[ct2][1] - m);
          v[ct2][2] = expf(v[ct2][2] - m);
          v[ct2][3] = expf(v[ct2][3] - m);
          s += (v[ct2][0] + v[ct2][1]) + (v[ct2][2] + v[ct2][3]);
        }
      }
      s += __shfl_xor(s, 16, 64);
      s += __shfl_xor(s, 32, 64);
      float denom = s + (float)(K_ASSIGN - KPG) * expf(-m);
      float scale = 1.0f / (s + 1e-13f * denom);
      if (xrow < NPG) {
#pragma unroll
        for (int ct2 = 0; ct2 < 7; ct2++) {
          int col0 = 16 * ct2 + 4 * lg;
          if (col0 < KPG) {
            ushort4 pk;
            pk.x = f2bf(v[ct2][0] * scale);
            pk.y = f2bf(v[ct2][1] * scale);
            pk.z = f2bf(v[ct2][2] * scale);
            pk.w = f2bf(v[ct2][3] * scale);
            *(ushort4*)(assign_bf + ((size_t)g * NPG + xrow) * KPG + col0) = pk;
          }
        }
      }
    }
  }
}

// ---------------------------------------------------------------------------
// tmp_bf[n] = sum_{e->n} assign_bf[src_e]. Standalone high-occupancy gather.
// ---------------------------------------------------------------------------
__global__ __launch_bounds__(256) void tmp_gather(
    const int* __restrict__ rowstart, const int* __restrict__ bucket,
    const unsigned short* __restrict__ assign_bf, unsigned short* __restrict__ tmp_bf) {
  int bid = (int)(blockIdx.x & 7) * 1000 + (int)(blockIdx.x >> 3);
  int n = bid * 4 + (threadIdx.x >> 6);
  int lane = threadIdx.x & 63;
  int rs = rowstart[n], re = rowstart[n + 1];
  int deg = re - rs;
  int lc = (lane < 50) ? lane : 0;
  const unsigned* ab = (const unsigned*)assign_bf;
  float ax = 0.f, ay = 0.f;
  for (int base = 0; base < deg; base += 64) {
    int cnt = deg - base;
    if (cnt > 64) cnt = 64;
    int myidx = (lane < cnt) ? bucket[rs + base + lane] : 0;
    int j = 0;
    for (; j + 8 <= cnt; j += 8) {
      int s0 = __shfl(myidx, j + 0), s1 = __shfl(myidx, j + 1);
      int s2 = __shfl(myidx, j + 2), s3 = __shfl(myidx, j + 3);
      int s4 = __shfl(myidx, j + 4), s5 = __shfl(myidx, j + 5);
      int s6 = __shfl(myidx, j + 6), s7 = __shfl(myidx, j + 7);
      unsigned v0 = ab[(size_t)s0 * 50 + lc];
      unsigned v1 = ab[(size_t)s1 * 50 + lc];
      unsigned v2 = ab[(size_t)s2 * 50 + lc];
      unsigned v3 = ab[(size_t)s3 * 50 + lc];
      unsigned v4 = ab[(size_t)s4 * 50 + lc];
      unsigned v5 = ab[(size_t)s5 * 50 + lc];
      unsigned v6 = ab[(size_t)s6 * 50 + lc];
      unsigned v7 = ab[(size_t)s7 * 50 + lc];
      ax += ((bfLO(v0) + bfLO(v1)) + (bfLO(v2) + bfLO(v3))) +
            ((bfLO(v4) + bfLO(v5)) + (bfLO(v6) + bfLO(v7)));
      ay += ((bfHI(v0) + bfHI(v1)) + (bfHI(v2) + bfHI(v3))) +
            ((bfHI(v4) + bfHI(v5)) + (bfHI(v6) + bfHI(v7)));
    }
    for (; j < cnt; j++) {
      int s0 = __shfl(myidx, j);
      unsigned v = ab[(size_t)s0 * 50 + lc];
      ax += bfLO(v);
      ay += bfHI(v);
    }
  }
  if (lane < 50) {
    unsigned o = ((unsigned)f2bf(ay) << 16) | f2bf(ax);
    ((unsigned*)tmp_bf)[(size_t)n * 50 + lane] = o;
  }
}

// ---------------------------------------------------------------------------
// pool (blocks 0..255) + adj (blocks 256..511), MFMA over K=n.
// ---------------------------------------------------------------------------
#define PA_STR 72
#define PA_CHN 128
__global__ __launch_bounds__(256) void pool_adj_mfma(
    const unsigned short* __restrict__ assign_bf,
    const unsigned short* __restrict__ feat_bf,
    const unsigned short* __restrict__ tmp_bf,
    float* __restrict__ out_adj, float* __restrict__ out_hpool) {
  __shared__ __align__(16) unsigned short as[112 * PA_STR];
  __shared__ __align__(16) unsigned short bs[128 * PA_STR];
  bool is_pool = blockIdx.x < 256;
  int bb = is_pool ? blockIdx.x : blockIdx.x - 256;
  int g = bb >> 4, ch = bb & 15;
  int nbase = ch * PA_CHN;
  int lim = NPG - nbase;
  if (lim > PA_CHN) lim = PA_CHN;
  int t = threadIdx.x;
  int w = t >> 6, l = t & 63, lr = l & 15, lg = l >> 4;
  const unsigned* au = (const unsigned*)assign_bf;
  const unsigned* fu = (const unsigned*)feat_bf;
  const unsigned* tu = (const unsigned*)tmp_bf;

  for (int i = t; i < 12 * PA_STR; i += 256) as[100 * PA_STR + i] = 0;
  for (int i = t; i < 28 * PA_STR; i += 256) bs[100 * PA_STR + i] = 0;

  f32x4 acc[7][2];
#pragma unroll
  for (int i = 0; i < 7; i++) {
    acc[i][0] = (f32x4){0.f, 0.f, 0.f, 0.f};
    acc[i][1] = (f32x4){0.f, 0.f, 0.f, 0.f};
  }

  for (int kt = 0; kt < 2; kt++) {
    int nt0 = kt * 64;
    __syncthreads();
#pragma unroll
    for (int i = 0; i < 13; i++) {
      int idx = t + 256 * i;
      if (idx < 3200) {
        int r = idx / 50, cu = idx % 50;
        int nl = nt0 + r;
        unsigned v = 0;
        if (nl < lim) v = au[(size_t)(g * NPG + nbase + nl) * 50 + cu];
        as[(2 * cu) * PA_STR + r] = (unsigned short)(v & 0xFFFFu);
        as[(2 * cu + 1) * PA_STR + r] = (unsigned short)(v >> 16);
      }
    }
    if (is_pool) {
#pragma unroll
      for (int i = 0; i < 16; i++) {
        int idx = t + 256 * i;
        int r = idx >> 6, cu = idx & 63;
        int nl = nt0 + r;
        unsigned v = 0;
        if (nl < lim) v = fu[(size_t)(g * NPG + nbase + nl) * 64 + cu];
        bs[(2 * cu) * PA_STR + r] = (unsigned short)(v & 0xFFFFu);
        bs[(2 * cu + 1) * PA_STR + r] = (unsigned short)(v >> 16);
      }
    } else {
#pragma unroll
      for (int i = 0; i < 13; i++) {
        int idx = t + 256 * i;
        if (idx < 3200) {
          int r = idx / 50, cu = idx % 50;
          int nl = nt0 + r;
          unsigned v = 0;
          if (nl < lim) v = tu[(size_t)(g * NPG + nbase + nl) * 50 + cu];
          bs[(2 * cu) * PA_STR + r] = (unsigned short)(v & 0xFFFFu);
          bs[(2 * cu + 1) * PA_STR + r] = (unsigned short)(v >> 16);
        }
      }
    }
    __syncthreads();
#pragma unroll
    for (int kc = 0; kc < 2; kc++) {
      bf16x8 afr[7];
#pragma unroll
      for (int mt = 0; mt < 7; mt++)
        afr[mt] = *(bf16x8*)&as[(16 * mt + lr) * PA_STR + 32 * kc + 8 * lg];
#pragma unroll
      for (int nt2 = 0; nt2 < 2; nt2++) {
        int nt = 2 * w + nt2;
        bf16x8 bfr = *(bf16x8*)&bs[(16 * nt + lr) * PA_STR + 32 * kc + 8 * lg];
#pragma unroll
        for (int mt = 0; mt < 7; mt++)
          acc[mt][nt2] =
              __builtin_amdgcn_mfma_f32_16x16x32_bf16(afr[mt], bfr, acc[mt][nt2], 0, 0, 0);
      }
    }
  }

  if (is_pool) {
#pragma unroll
    for (int mt = 0; mt < 7; mt++)
#pragma unroll
      for (int nt2 = 0; nt2 < 2; nt2++) {
        int nt = 2 * w + nt2;
#pragma unroll
        for (int r = 0; r < 4; r++) {
          int m = 16 * mt + 4 * lg + r;
          if (m < KPG)
            atomicAdd(out_hpool + ((size_t)g * KPG + m) * 128 + 16 * nt + lr,
                      acc[mt][nt2][r]);
        }
      }
  } else {
#pragma unroll
    for (int mt = 0; mt < 7; mt++)
#pragma unroll
      for (int nt2 = 0; nt2 < 2; nt2++) {
        int nt = 2 * w + nt2;
        if (nt < 7) {
          int k2 = 16 * nt + lr;
          if (k2 < KPG) {
#pragma unroll
            for (int r = 0; r < 4; r++) {
              int m = 16 * mt + 4 * lg + r;
              if (m < KPG)
                atomicAdd(out_adj + ((size_t)g * KPG + m) * K_ASSIGN + g * KPG + k2,
                          acc[mt][nt2][r]);
            }
          }
        }
      }
  }
}

extern "C" void kernel_launch(void* const* d_in, const int* in_sizes, int n_in,
                              void* d_out, int out_size, void* d_ws,
                              size_t ws_size, hipStream_t stream) {
  (void)in_sizes; (void)n_in; (void)ws_size;
  const float* h   = (const float*)d_in[0];
  const int*   src = (const int*)d_in[1];
  const int*   dst = (const int*)d_in[2];
  const float* W1f = (const float*)d_in[3];
  const float* b1f = (const float*)d_in[4];
  const float* W2f = (const float*)d_in[5];
  const float* b2f = (const float*)d_in[6];
  const float* W1p = (const float*)d_in[7];
  const float* b1p = (const float*)d_in[8];
  const float* W2p = (const float*)d_in[9];
  const float* b2p = (const float*)d_in[10];

  float* out_adj   = (float*)d_out;
  float* out_hpool = out_adj + (size_t)K_ASSIGN * K_ASSIGN;

  char* ws = (char*)d_ws;
  int* deg_cnt  = (int*)(ws + 0);            //   128,000
  int* rowstart = (int*)(ws + 128000);       //   128,032
  int* cursor   = (int*)(ws + 256032);       //   128,000
  int* bucket   = (int*)(ws + 384032);       // 2,048,000
  unsigned short* h_bf      = (unsigned short*)(ws + 2432032);   // 8,192,000
  unsigned short* x_bf      = (unsigned short*)(ws + 10624032);  // 8,192,000
  unsigned short* feat_bf   = (unsigned short*)(ws + 18816032);  // 8,192,000
  unsigned short* assign_bf = (unsigned short*)(ws + 27008032);  // 6,400,000
  unsigned short* tmp_bf    = (unsigned short*)(ws + 33408032);  // 6,400,000
  unsigned short* w1f_t     = (unsigned short*)(ws + 39808032);  //    32,768
  unsigned short* w2f_t     = (unsigned short*)(ws + 39840800);  //    32,768
  unsigned short* w1p_t     = (unsigned short*)(ws + 39873568);  //   409,600
  unsigned short* w2p_t     = (unsigned short*)(ws + 40283168);  // 5,120,000

  hipMemsetAsync(deg_cnt, 0, 128000, stream);
  hipMemsetAsync(cursor, 0, 128000, stream);
  hipMemsetAsync(d_out, 0, (size_t)out_size * sizeof(float), stream);

  // transposes + h->bf16 + edge histogram
  prep_all<<<8732, 256, 0, stream>>>(W1f, W2f, W1p, W2p, w1f_t, w2f_t, w1p_t,
                                     w2p_t, h, h_bf, dst, deg_cnt);

  // CSR build
  scan_counts<<<1, 1024, 0, stream>>>(deg_cnt, rowstart);
  edge_fill<<<N_EDGES / 256, 256, 0, stream>>>(src, dst, rowstart, cursor, bucket);

  // aggregation (gather, XCD-swizzled) -> x in bf16
  gin_gather<<<N_NODES / 4, 256, 0, stream>>>(rowstart, bucket, h_bf, x_bf);

  // feat MLP + assign MLP + softmax, one launch; weights direct from cache
  feat_assign<<<256 + N_NODES / 128, 512, 0, stream>>>(
      x_bf, w1f_t, b1f, w2f_t, b2f, feat_bf,
      w1p_t, b1p, w2p_t, b2p, assign_bf);

  // adj @ assign via gather (standalone, high-occupancy)
  tmp_gather<<<N_NODES / 4, 256, 0, stream>>>(rowstart, bucket, assign_bf, tmp_bf);

  // outputs (MFMA)
  pool_adj_mfma<<<512, 256, 0, stream>>>(assign_bf, feat_bf, tmp_bf,
                                         out_adj, out_hpool);
}

// Round 14
// 216.792 us; speedup vs baseline: 1.3318x; 1.3318x over previous
//
#include <hip/hip_runtime.h>

#define N_NODES 32000
#define NPG     2000
#define NGRAPH  16
#define K_ASSIGN 1600
#define KPG     100
#define D_FEAT  128
#define N_EDGES 512000

typedef float f32x4 __attribute__((ext_vector_type(4)));
typedef __bf16 bf16x8 __attribute__((ext_vector_type(8)));

union FragU { unsigned u[4]; bf16x8 v; };

__device__ __forceinline__ float frelu(float v) { return fmaxf(v, 0.0f); }

__device__ __forceinline__ unsigned short f2bf(float f) {
  unsigned u = __float_as_uint(f);
  u += 0x7FFFu + ((u >> 16) & 1u);
  return (unsigned short)(u >> 16);
}
__device__ __forceinline__ float bfLO(unsigned v) { return __uint_as_float(v << 16); }
__device__ __forceinline__ float bfHI(unsigned v) { return __uint_as_float(v & 0xFFFF0000u); }

// ---------------------------------------------------------------------------
// prep_all: weight transposes (f32->bf16 [C][R]) + h->bf16 + edge histogram.
// ---------------------------------------------------------------------------
__global__ __launch_bounds__(256) void prep_all(
    const float* __restrict__ W1f, const float* __restrict__ W2f,
    const float* __restrict__ W1p, const float* __restrict__ W2p,
    unsigned short* __restrict__ o1, unsigned short* __restrict__ o2,
    unsigned short* __restrict__ o3, unsigned short* __restrict__ o4,
    const float* __restrict__ h, unsigned short* __restrict__ h_bf,
    const int* __restrict__ dst, int* __restrict__ cnt) {
  __shared__ float tile[32][33];
  int b = blockIdx.x;
  int t = threadIdx.x;
  if (b >= 6732) {  // edge histogram
    int e = (b - 6732) * 256 + t;
    if (e < N_EDGES) atomicAdd(&cnt[dst[e]], 1);
    return;
  }
  if (b >= 2732) {  // h -> bf16
    int i = (b - 2732) * 256 + t;  // float4 index
    float4 v = ((const float4*)h)[i];
    ushort4 o;
    o.x = f2bf(v.x); o.y = f2bf(v.y); o.z = f2bf(v.z); o.w = f2bf(v.w);
    ((ushort4*)h_bf)[i] = o;
    return;
  }
  const float* in;
  unsigned short* out;
  int R, C, rb;
  if (b < 16)       { in = W1f; out = o1; R = 128;  C = 128;  rb = b; }
  else if (b < 32)  { in = W2f; out = o2; R = 128;  C = 128;  rb = b - 16; }
  else if (b < 232) { in = W1p; out = o3; R = 128;  C = 1600; rb = b - 32; }
  else              { in = W2p; out = o4; R = 1600; C = 1600; rb = b - 232; }
  int ct = C >> 5;
  int bc = rb % ct, br = rb / ct;
  int r0 = br * 32, c0 = bc * 32;
#pragma unroll
  for (int i = 0; i < 4; i++) {
    int r = (t >> 5) + i * 8, c = t & 31;
    tile[r][c] = in[(size_t)(r0 + r) * C + c0 + c];
  }
  __syncthreads();
#pragma unroll
  for (int i = 0; i < 4; i++) {
    int c = (t >> 5) + i * 8, r = t & 31;
    out[(size_t)(c0 + c) * R + r0 + r] = f2bf(tile[r][c]);
  }
}

// ---------------------------------------------------------------------------
// CSR scan: 1024 threads, 32 counts each (1000 active).
// ---------------------------------------------------------------------------
__global__ __launch_bounds__(1024) void scan_counts(
    const int* __restrict__ cnt, int* __restrict__ rowstart) {
  __shared__ int sums[1024];
  int t = threadIdx.x;
  int base = t * 32;
  int s = 0;
  if (t < 1000)
    for (int i = 0; i < 32; i++) s += cnt[base + i];
  sums[t] = s;
  __syncthreads();
  for (int off = 1; off < 1024; off <<= 1) {
    int v = (t >= off) ? sums[t - off] : 0;
    __syncthreads();
    sums[t] += v;
    __syncthreads();
  }
  if (t < 1000) {
    int run = (t == 0) ? 0 : sums[t - 1];
    for (int i = 0; i < 32; i++) {
      rowstart[base + i] = run;
      run += cnt[base + i];
    }
  }
  if (t == 999) rowstart[32000] = sums[999];
}

__global__ __launch_bounds__(256) void edge_fill(
    const int* __restrict__ src, const int* __restrict__ dst,
    const int* __restrict__ rowstart, int* __restrict__ cursor,
    int* __restrict__ bucket) {
  int e = blockIdx.x * 256 + threadIdx.x;
  if (e < N_EDGES) {
    int d = dst[e];
    int pos = atomicAdd(&cursor[d], 1);
    bucket[rowstart[d] + pos] = src[e];
  }
}

// ---------------------------------------------------------------------------
// Gather aggregation + compute_x: x_bf[n] = bf16(h_bf[n] + mean h_bf[src]).
// XCD-chunked block swizzle (8000%8==0, bijective). No LDS, low VGPR.
// ---------------------------------------------------------------------------
__global__ __launch_bounds__(256) void gin_gather(
    const int* __restrict__ rowstart, const int* __restrict__ bucket,
    const unsigned short* __restrict__ h_bf, unsigned short* __restrict__ x_bf) {
  int bid = (int)(blockIdx.x & 7) * 1000 + (int)(blockIdx.x >> 3);
  int n = bid * 4 + (threadIdx.x >> 6);
  int lane = threadIdx.x & 63;
  int rs = rowstart[n], re = rowstart[n + 1];
  const unsigned* hb = (const unsigned*)h_bf;
  float ax = 0.f, ay = 0.f;
  int e = rs;
  for (; e + 4 <= re; e += 4) {
    unsigned v0 = hb[(size_t)bucket[e] * 64 + lane];
    unsigned v1 = hb[(size_t)bucket[e + 1] * 64 + lane];
    unsigned v2 = hb[(size_t)bucket[e + 2] * 64 + lane];
    unsigned v3 = hb[(size_t)bucket[e + 3] * 64 + lane];
    ax += (bfLO(v0) + bfLO(v1)) + (bfLO(v2) + bfLO(v3));
    ay += (bfHI(v0) + bfHI(v1)) + (bfHI(v2) + bfHI(v3));
  }
  for (; e < re; e++) {
    unsigned v = hb[(size_t)bucket[e] * 64 + lane];
    ax += bfLO(v);
    ay += bfHI(v);
  }
  float invd = 1.0f / fmaxf((float)(re - rs), 1.0f);
  unsigned hv = hb[(size_t)n * 64 + lane];
  unsigned o = ((unsigned)f2bf(bfHI(hv) + ay * invd) << 16) |
               f2bf(bfLO(hv) + ax * invd);
  ((unsigned*)x_bf)[(size_t)n * 64 + lane] = o;
}

// ---------------------------------------------------------------------------
// MERGED feat + assign. Blocks [0,256): fused assign+softmax (128 rows each);
// blocks [256,506): feat 2-layer MLP (128 rows each). Both 512 threads.
// LDS-staged weights + double buffering (r13 showed direct-global loses 2x
// to latency; r12 showed gather fusion loses L2 locality — this is the
// surviving structure).
// ---------------------------------------------------------------------------
#define FF_STR 136
#define FA_WS 136
#define FA_PS 72
#define FA_W1OFF 17408
#define FA_W2BASE 34816
#define FA_W2OFF 16128
__global__ __launch_bounds__(512) void feat_assign(
    const unsigned short* __restrict__ x_bf,
    const unsigned short* __restrict__ w1ft, const float* __restrict__ b1f,
    const unsigned short* __restrict__ w2ft, const float* __restrict__ b2f,
    unsigned short* __restrict__ feat_bf,
    const unsigned short* __restrict__ w1t, const float* __restrict__ b1p,
    const unsigned short* __restrict__ w2t, const float* __restrict__ b2p,
    unsigned short* __restrict__ assign_bf) {
  __shared__ __align__(16) unsigned char smem[69632];
  int t = threadIdx.x;
  int w = t >> 6, l = t & 63, lr = l & 15, lg = l >> 4;

  if (blockIdx.x >= 256) {
    // ---------------- feat path ----------------
    unsigned short* xa = (unsigned short*)smem;            // xt, then x1
    unsigned short* ws = (unsigned short*)(smem + 34816);  // W1, then W2
    size_t base = (size_t)(blockIdx.x - 256) * 128;

#pragma unroll
    for (int i = 0; i < 4; i++) {
      int fi = t + 512 * i;
      int r = fi >> 4, u8 = (fi & 15) * 8;
      *(uint4*)&xa[r * FF_STR + u8] = *(const uint4*)(x_bf + (base + r) * 128 + u8);
      *(uint4*)&ws[r * FF_STR + u8] = *(const uint4*)(w1ft + (size_t)r * 128 + u8);
    }
    __syncthreads();

    int myrow = 16 * w + lr;
    bf16x8 af[4];
#pragma unroll
    for (int kc = 0; kc < 4; kc++)
      af[kc] = *(bf16x8*)&xa[myrow * FF_STR + 32 * kc + 8 * lg];

    f32x4 p[8];
#pragma unroll
    for (int ntk = 0; ntk < 8; ntk++) {
      p[ntk] = (f32x4){0.f, 0.f, 0.f, 0.f};
      int c = 16 * ntk + lr;
#pragma unroll
      for (int kc = 0; kc < 4; kc++) {
        bf16x8 wf = *(bf16x8*)&ws[c * FF_STR + 32 * kc + 8 * lg];
        p[ntk] = __builtin_amdgcn_mfma_f32_16x16x32_bf16(wf, af[kc], p[ntk], 0, 0, 0);
      }
    }
    __syncthreads();

#pragma unroll
    for (int ntk = 0; ntk < 8; ntk++) {
      int kk0 = 16 * ntk + 4 * lg;
      float4 b1 = *(const float4*)(b1f + kk0);
      ushort4 pk;
      pk.x = f2bf(frelu(p[ntk][0] + b1.x));
      pk.y = f2bf(frelu(p[ntk][1] + b1.y));
      pk.z = f2bf(frelu(p[ntk][2] + b1.z));
      pk.w = f2bf(frelu(p[ntk][3] + b1.w));
      *(ushort4*)&xa[myrow * FF_STR + kk0] = pk;
    }
#pragma unroll
    for (int i = 0; i < 4; i++) {
      int fi = t + 512 * i;
      int r = fi >> 4, u8 = (fi & 15) * 8;
      *(uint4*)&ws[r * FF_STR + u8] = *(const uint4*)(w2ft + (size_t)r * 128 + u8);
    }
    __syncthreads();

    bf16x8 a2[4];
#pragma unroll
    for (int kc = 0; kc < 4; kc++)
      a2[kc] = *(bf16x8*)&xa[myrow * FF_STR + 32 * kc + 8 * lg];
#pragma unroll
    for (int nt = 0; nt < 8; nt++) {
      f32x4 q = (f32x4){0.f, 0.f, 0.f, 0.f};
      int c = 16 * nt + lr;
#pragma unroll
      for (int kc = 0; kc < 4; kc++) {
        bf16x8 wf = *(bf16x8*)&ws[c * FF_STR + 32 * kc + 8 * lg];
        q = __builtin_amdgcn_mfma_f32_16x16x32_bf16(wf, a2[kc], q, 0, 0, 0);
      }
      int c0 = 16 * nt + 4 * lg;
      float4 b2 = *(const float4*)(b2f + c0);
      ushort4 pk;
      pk.x = f2bf(frelu(q[0] + b2.x));
      pk.y = f2bf(frelu(q[1] + b2.y));
      pk.z = f2bf(frelu(q[2] + b2.z));
      pk.w = f2bf(frelu(q[3] + b2.w));
      *(ushort4*)&feat_bf[(base + myrow) * 128 + c0] = pk;
    }
    return;
  }

  // ---------------- assign path ----------------
  unsigned short* xt = (unsigned short*)smem;
  int g = blockIdx.x >> 4;
  int row0 = (blockIdx.x & 15) << 7;
  int n0 = g * NPG + row0;

#pragma unroll
  for (int i = 0; i < 4; i++) {
    int fi = t + 512 * i;
    int r = fi >> 4, u8 = (fi & 15) * 8;
    uint4 v = make_uint4(0, 0, 0, 0);
    if (row0 + r < NPG) v = *(const uint4*)(x_bf + (size_t)(n0 + r) * 128 + u8);
    *(uint4*)&xt[r * FA_WS + u8] = v;
  }
  __syncthreads();

  int rh = w >> 1, h = w & 1;

  bf16x8 af[2][4];
#pragma unroll
  for (int ct = 0; ct < 2; ct++)
#pragma unroll
    for (int kc = 0; kc < 4; kc++)
      af[ct][kc] =
          *(bf16x8*)&xt[(32 * rh + 16 * ct + lr) * FA_WS + 32 * kc + 8 * lg];
  __syncthreads();  // xt region becomes w1 buffers

  {
    unsigned short* w1s = (unsigned short*)smem;
    unsigned short* w2s = (unsigned short*)(smem + FA_W2BASE);
#pragma unroll
    for (int i = 0; i < 2; i++) {
      int fi = t + 512 * i;
      int c = fi >> 4, u8 = (fi & 15) * 8;
      *(uint4*)&w1s[c * FA_WS + u8] = *(const uint4*)(w1t + (size_t)c * 128 + u8);
    }
#pragma unroll
    for (int i = 0; i < 2; i++) {
      int fi = t + 512 * i;
      if (fi < 896) {
        int c = fi >> 3, u8 = (fi & 7) * 8;
        uint4 v = make_uint4(0, 0, 0, 0);
        if (c < KPG)
          v = *(const uint4*)(w2t + (size_t)(g * KPG + c) * K_ASSIGN + u8);
        *(uint4*)&w2s[c * FA_PS + u8] = v;
      }
    }
  }
  __syncthreads();

  f32x4 acc[7][2];
#pragma unroll
  for (int i = 0; i < 7; i++) {
    acc[i][0] = (f32x4){0.f, 0.f, 0.f, 0.f};
    acc[i][1] = (f32x4){0.f, 0.f, 0.f, 0.f};
  }

  for (int cch = 0; cch < 25; cch++) {
    int cur = cch & 1;
    int k0 = cch * 64;
    const unsigned short* w1c = (const unsigned short*)(smem + cur * FA_W1OFF);
    const unsigned short* w2c =
        (const unsigned short*)(smem + FA_W2BASE + cur * FA_W2OFF);
    bool pf = (cch < 24);
    uint4 rA[2], rB[2];
    if (pf) {
      int k1 = k0 + 64;
#pragma unroll
      for (int i = 0; i < 2; i++) {
        int fi = t + 512 * i;
        int c = fi >> 4, u8 = (fi & 15) * 8;
        rA[i] = *(const uint4*)(w1t + (size_t)(k1 + c) * 128 + u8);
      }
#pragma unroll
      for (int i = 0; i < 2; i++) {
        int fi = t + 512 * i;
        rB[i] = make_uint4(0, 0, 0, 0);
        if (fi < 896) {
          int c = fi >> 3, u8 = (fi & 7) * 8;
          if (c < KPG)
            rB[i] = *(const uint4*)(w2t + (size_t)(g * KPG + c) * K_ASSIGN +
                                    k1 + u8);
        }
      }
    }

    f32x4 p[2][2];
    __builtin_amdgcn_s_setprio(1);
#pragma unroll
    for (int nt2 = 0; nt2 < 2; nt2++) {
      p[nt2][0] = (f32x4){0.f, 0.f, 0.f, 0.f};
      p[nt2][1] = (f32x4){0.f, 0.f, 0.f, 0.f};
      int nt = 2 * h + nt2;
#pragma unroll
      for (int kc = 0; kc < 4; kc++) {
        bf16x8 wf = *(bf16x8*)&w1c[(16 * nt + lr) * FA_WS + 32 * kc + 8 * lg];
        p[nt2][0] = __builtin_amdgcn_mfma_f32_16x16x32_bf16(wf, af[0][kc],
                                                            p[nt2][0], 0, 0, 0);
        p[nt2][1] = __builtin_amdgcn_mfma_f32_16x16x32_bf16(wf, af[1][kc],
                                                            p[nt2][1], 0, 0, 0);
      }
    }
    __builtin_amdgcn_s_setprio(0);
    unsigned q[2][2][2];
#pragma unroll
    for (int nt2 = 0; nt2 < 2; nt2++) {
      int kkb = k0 + 16 * (2 * h + nt2) + 4 * lg;
      float4 b1 = *(const float4*)(b1p + kkb);
#pragma unroll
      for (int ct = 0; ct < 2; ct++) {
        float r0 = frelu(p[nt2][ct][0] + b1.x);
        float r1 = frelu(p[nt2][ct][1] + b1.y);
        float r2 = frelu(p[nt2][ct][2] + b1.z);
        float r3 = frelu(p[nt2][ct][3] + b1.w);
        q[nt2][ct][0] = ((unsigned)f2bf(r1) << 16) | f2bf(r0);
        q[nt2][ct][1] = ((unsigned)f2bf(r3) << 16) | f2bf(r2);
      }
    }
    int sA = lr + 32 * (lg & 1);
    int sB = sA + 16;
    bool hi = (lg >= 2);
    FragU pa[2];
#pragma unroll
    for (int ct = 0; ct < 2; ct++) {
      unsigned a0 = (unsigned)__shfl((int)q[0][ct][0], sA, 64);
      unsigned b0 = (unsigned)__shfl((int)q[1][ct][0], sA, 64);
      unsigned a1 = (unsigned)__shfl((int)q[0][ct][1], sA, 64);
      unsigned b1u = (unsigned)__shfl((int)q[1][ct][1], sA, 64);
      unsigned a2 = (unsigned)__shfl((int)q[0][ct][0], sB, 64);
      unsigned b2u = (unsigned)__shfl((int)q[1][ct][0], sB, 64);
      unsigned a3 = (unsigned)__shfl((int)q[0][ct][1], sB, 64);
      unsigned b3u = (unsigned)__shfl((int)q[1][ct][1], sB, 64);
      pa[ct].u[0] = hi ? b0 : a0;
      pa[ct].u[1] = hi ? b1u : a1;
      pa[ct].u[2] = hi ? b2u : a2;
      pa[ct].u[3] = hi ? b3u : a3;
    }
    // prefetched chunk -> alternate buffers before phase-2 (drains under MFMA)
    if (pf) {
      unsigned short* w1n = (unsigned short*)(smem + (cur ^ 1) * FA_W1OFF);
      unsigned short* w2n =
          (unsigned short*)(smem + FA_W2BASE + (cur ^ 1) * FA_W2OFF);
#pragma unroll
      for (int i = 0; i < 2; i++) {
        int fi = t + 512 * i;
        int c = fi >> 4, u8 = (fi & 15) * 8;
        *(uint4*)&w1n[c * FA_WS + u8] = rA[i];
      }
#pragma unroll
      for (int i = 0; i < 2; i++) {
        int fi = t + 512 * i;
        if (fi < 896) {
          int c = fi >> 3, u8 = (fi & 7) * 8;
          *(uint4*)&w2n[c * FA_PS + u8] = rB[i];
        }
      }
    }
    __builtin_amdgcn_s_setprio(1);
#pragma unroll
    for (int ct2 = 0; ct2 < 7; ct2++) {
      bf16x8 wv = *(bf16x8*)&w2c[(16 * ct2 + lr) * FA_PS + 32 * h + 8 * lg];
      acc[ct2][0] = __builtin_amdgcn_mfma_f32_16x16x32_bf16(wv, pa[0].v,
                                                            acc[ct2][0], 0, 0, 0);
      acc[ct2][1] = __builtin_amdgcn_mfma_f32_16x16x32_bf16(wv, pa[1].v,
                                                            acc[ct2][1], 0, 0, 0);
    }
    __builtin_amdgcn_s_setprio(0);
    __syncthreads();
  }

  // cross-h reduction
  float* red = (float*)smem;
  if (h == 1) {
#pragma unroll
    for (int ct2 = 0; ct2 < 7; ct2++)
#pragma unroll
      for (int ct = 0; ct < 2; ct++)
        *(f32x4*)&red[((rh * 14 + ct2 * 2 + ct) * 64 + l) * 4] = acc[ct2][ct];
  }
  __syncthreads();
  if (h == 0) {
#pragma unroll
    for (int ct2 = 0; ct2 < 7; ct2++)
#pragma unroll
      for (int ct = 0; ct < 2; ct++)
        acc[ct2][ct] += *(f32x4*)&red[((rh * 14 + ct2 * 2 + ct) * 64 + l) * 4];

    // fused masked softmax
#pragma unroll
    for (int ct = 0; ct < 2; ct++) {
      int xrow = row0 + 32 * rh + 16 * ct + lr;
      float v[7][4];
      float m = 0.0f;
#pragma unroll
      for (int ct2 = 0; ct2 < 7; ct2++) {
        int col0 = 16 * ct2 + 4 * lg;
        if (col0 < KPG) {
          float4 b2 = *(const float4*)(b2p + g * KPG + col0);
          v[ct2][0] = frelu(acc[ct2][ct][0] + b2.x);
          v[ct2][1] = frelu(acc[ct2][ct][1] + b2.y);
          v[ct2][2] = frelu(acc[ct2][ct][2] + b2.z);
          v[ct2][3] = frelu(acc[ct2][ct][3] + b2.w);
          m = fmaxf(m, fmaxf(fmaxf(v[ct2][0], v[ct2][1]),
                             fmaxf(v[ct2][2], v[ct2][3])));
        }
      }
      m = fmaxf(m, __shfl_xor(m, 16, 64));
      m = fmaxf(m, __shfl_xor(m, 32, 64));
      float s = 0.0f;
#pragma unroll
      for (int ct2 = 0; ct2 < 7; ct2++) {
        int col0 = 16 * ct2 + 4 * lg;
        if (col0 < KPG) {
          v[ct2][0] = expf(v[ct2][0] - m);
          v[ct2][1] = expf(v[ct2][1] - m);
          v[ct2][2] = expf(v[ct2][2] - m);
          v[ct2][3] = expf(v[ct2][3] - m);
          s += (v[ct2][0] + v[ct2][1]) + (v[ct2][2] + v[ct2][3]);
        }
      }
      s += __shfl_xor(s, 16, 64);
      s += __shfl_xor(s, 32, 64);
      float denom = s + (float)(K_ASSIGN - KPG) * expf(-m);
      float scale = 1.0f / (s + 1e-13f * denom);
      if (xrow < NPG) {
#pragma unroll
        for (int ct2 = 0; ct2 < 7; ct2++) {
          int col0 = 16 * ct2 + 4 * lg;
          if (col0 < KPG) {
            ushort4 pk;
            pk.x = f2bf(v[ct2][0] * scale);
            pk.y = f2bf(v[ct2][1] * scale);
            pk.z = f2bf(v[ct2][2] * scale);
            pk.w = f2bf(v[ct2][3] * scale);
            *(ushort4*)(assign_bf + ((size_t)g * NPG + xrow) * KPG + col0) = pk;
          }
        }
      }
    }
  }
}

// ---------------------------------------------------------------------------
// tmp_bf[n] = sum_{e->n} assign_bf[src_e]. Standalone: no LDS, low VGPR ->
// high occupancy (latency-bound gather needs TLP).
// ---------------------------------------------------------------------------
__global__ __launch_bounds__(256) void tmp_gather(
    const int* __restrict__ rowstart, const int* __restrict__ bucket,
    const unsigned short* __restrict__ assign_bf, unsigned short* __restrict__ tmp_bf) {
  int bid = (int)(blockIdx.x & 7) * 1000 + (int)(blockIdx.x >> 3);
  int n = bid * 4 + (threadIdx.x >> 6);
  int lane = threadIdx.x & 63;
  if (lane >= 50) return;
  int rs = rowstart[n], re = rowstart[n + 1];
  const unsigned* ab = (const unsigned*)assign_bf;
  float ax = 0.f, ay = 0.f;
  int e = rs;
  for (; e + 4 <= re; e += 4) {
    unsigned v0 = ab[(size_t)bucket[e] * 50 + lane];
    unsigned v1 = ab[(size_t)bucket[e + 1] * 50 + lane];
    unsigned v2 = ab[(size_t)bucket[e + 2] * 50 + lane];
    unsigned v3 = ab[(size_t)bucket[e + 3] * 50 + lane];
    ax += (bfLO(v0) + bfLO(v1)) + (bfLO(v2) + bfLO(v3));
    ay += (bfHI(v0) + bfHI(v1)) + (bfHI(v2) + bfHI(v3));
  }
  for (; e < re; e++) {
    unsigned v = ab[(size_t)bucket[e] * 50 + lane];
    ax += bfLO(v);
    ay += bfHI(v);
  }
  unsigned o = ((unsigned)f2bf(ay) << 16) | f2bf(ax);
  ((unsigned*)tmp_bf)[(size_t)n * 50 + lane] = o;
}

// ---------------------------------------------------------------------------
// pool (blocks 0..255) + adj (blocks 256..511), MFMA over K=n.
// ---------------------------------------------------------------------------
#define PA_STR 72
#define PA_CHN 128
__global__ __launch_bounds__(256) void pool_adj_mfma(
    const unsigned short* __restrict__ assign_bf,
    const unsigned short* __restrict__ feat_bf,
    const unsigned short* __restrict__ tmp_bf,
    float* __restrict__ out_adj, float* __restrict__ out_hpool) {
  __shared__ __align__(16) unsigned short as[112 * PA_STR];
  __shared__ __align__(16) unsigned short bs[128 * PA_STR];
  bool is_pool = blockIdx.x < 256;
  int bb = is_pool ? blockIdx.x : blockIdx.x - 256;
  int g = bb >> 4, ch = bb & 15;
  int nbase = ch * PA_CHN;
  int lim = NPG - nbase;
  if (lim > PA_CHN) lim = PA_CHN;
  int t = threadIdx.x;
  int w = t >> 6, l = t & 63, lr = l & 15, lg = l >> 4;
  const unsigned* au = (const unsigned*)assign_bf;
  const unsigned* fu = (const unsigned*)feat_bf;
  const unsigned* tu = (const unsigned*)tmp_bf;

  for (int i = t; i < 12 * PA_STR; i += 256) as[100 * PA_STR + i] = 0;
  for (int i = t; i < 28 * PA_STR; i += 256) bs[100 * PA_STR + i] = 0;

  f32x4 acc[7][2];
#pragma unroll
  for (int i = 0; i < 7; i++) {
    acc[i][0] = (f32x4){0.f, 0.f, 0.f, 0.f};
    acc[i][1] = (f32x4){0.f, 0.f, 0.f, 0.f};
  }

  for (int kt = 0; kt < 2; kt++) {
    int nt0 = kt * 64;
    __syncthreads();
#pragma unroll
    for (int i = 0; i < 13; i++) {
      int idx = t + 256 * i;
      if (idx < 3200) {
        int r = idx / 50, cu = idx % 50;
        int nl = nt0 + r;
        unsigned v = 0;
        if (nl < lim) v = au[(size_t)(g * NPG + nbase + nl) * 50 + cu];
        as[(2 * cu) * PA_STR + r] = (unsigned short)(v & 0xFFFFu);
        as[(2 * cu + 1) * PA_STR + r] = (unsigned short)(v >> 16);
      }
    }
    if (is_pool) {
#pragma unroll
      for (int i = 0; i < 16; i++) {
        int idx = t + 256 * i;
        int r = idx >> 6, cu = idx & 63;
        int nl = nt0 + r;
        unsigned v = 0;
        if (nl < lim) v = fu[(size_t)(g * NPG + nbase + nl) * 64 + cu];
        bs[(2 * cu) * PA_STR + r] = (unsigned short)(v & 0xFFFFu);
        bs[(2 * cu + 1) * PA_STR + r] = (unsigned short)(v >> 16);
      }
    } else {
#pragma unroll
      for (int i = 0; i < 13; i++) {
        int idx = t + 256 * i;
        if (idx < 3200) {
          int r = idx / 50, cu = idx % 50;
          int nl = nt0 + r;
          unsigned v = 0;
          if (nl < lim) v = tu[(size_t)(g * NPG + nbase + nl) * 50 + cu];
          bs[(2 * cu) * PA_STR + r] = (unsigned short)(v & 0xFFFFu);
          bs[(2 * cu + 1) * PA_STR + r] = (unsigned short)(v >> 16);
        }
      }
    }
    __syncthreads();
#pragma unroll
    for (int kc = 0; kc < 2; kc++) {
      bf16x8 afr[7];
#pragma unroll
      for (int mt = 0; mt < 7; mt++)
        afr[mt] = *(bf16x8*)&as[(16 * mt + lr) * PA_STR + 32 * kc + 8 * lg];
#pragma unroll
      for (int nt2 = 0; nt2 < 2; nt2++) {
        int nt = 2 * w + nt2;
        bf16x8 bfr = *(bf16x8*)&bs[(16 * nt + lr) * PA_STR + 32 * kc + 8 * lg];
#pragma unroll
        for (int mt = 0; mt < 7; mt++)
          acc[mt][nt2] =
              __builtin_amdgcn_mfma_f32_16x16x32_bf16(afr[mt], bfr, acc[mt][nt2], 0, 0, 0);
      }
    }
  }

  if (is_pool) {
#pragma unroll
    for (int mt = 0; mt < 7; mt++)
#pragma unroll
      for (int nt2 = 0; nt2 < 2; nt2++) {
        int nt = 2 * w + nt2;
#pragma unroll
        for (int r = 0; r < 4; r++) {
          int m = 16 * mt + 4 * lg + r;
          if (m < KPG)
            atomicAdd(out_hpool + ((size_t)g * KPG + m) * 128 + 16 * nt + lr,
                      acc[mt][nt2][r]);
        }
      }
  } else {
#pragma unroll
    for (int mt = 0; mt < 7; mt++)
#pragma unroll
      for (int nt2 = 0; nt2 < 2; nt2++) {
        int nt = 2 * w + nt2;
        if (nt < 7) {
          int k2 = 16 * nt + lr;
          if (k2 < KPG) {
#pragma unroll
            for (int r = 0; r < 4; r++) {
              int m = 16 * mt + 4 * lg + r;
              if (m < KPG)
                atomicAdd(out_adj + ((size_t)g * KPG + m) * K_ASSIGN + g * KPG + k2,
                          acc[mt][nt2][r]);
            }
          }
        }
      }
  }
}

extern "C" void kernel_launch(void* const* d_in, const int* in_sizes, int n_in,
                              void* d_out, int out_size, void* d_ws,
                              size_t ws_size, hipStream_t stream) {
  (void)in_sizes; (void)n_in; (void)ws_size;
  const float* h   = (const float*)d_in[0];
  const int*   src = (const int*)d_in[1];
  const int*   dst = (const int*)d_in[2];
  const float* W1f = (const float*)d_in[3];
  const float* b1f = (const float*)d_in[4];
  const float* W2f = (const float*)d_in[5];
  const float* b2f = (const float*)d_in[6];
  const float* W1p = (const float*)d_in[7];
  const float* b1p = (const float*)d_in[8];
  const float* W2p = (const float*)d_in[9];
  const float* b2p = (const float*)d_in[10];

  float* out_adj   = (float*)d_out;
  float* out_hpool = out_adj + (size_t)K_ASSIGN * K_ASSIGN;

  char* ws = (char*)d_ws;
  // deg_cnt and cursor adjacent -> single memset launch clears both.
  int* deg_cnt  = (int*)(ws + 0);            //   128,000
  int* cursor   = (int*)(ws + 128000);       //   128,000
  int* rowstart = (int*)(ws + 256000);       //   128,032
  int* bucket   = (int*)(ws + 384032);       // 2,048,000
  unsigned short* h_bf      = (unsigned short*)(ws + 2432032);   // 8,192,000
  unsigned short* x_bf      = (unsigned short*)(ws + 10624032);  // 8,192,000
  unsigned short* feat_bf   = (unsigned short*)(ws + 18816032);  // 8,192,000
  unsigned short* assign_bf = (unsigned short*)(ws + 27008032);  // 6,400,000
  unsigned short* tmp_bf    = (unsigned short*)(ws + 33408032);  // 6,400,000
  unsigned short* w1f_t     = (unsigned short*)(ws + 39808032);  //    32,768
  unsigned short* w2f_t     = (unsigned short*)(ws + 39840800);  //    32,768
  unsigned short* w1p_t     = (unsigned short*)(ws + 39873568);  //   409,600
  unsigned short* w2p_t     = (unsigned short*)(ws + 40283168);  // 5,120,000

  hipMemsetAsync(deg_cnt, 0, 256000, stream);  // deg_cnt + cursor
  hipMemsetAsync(d_out, 0, (size_t)out_size * sizeof(float), stream);

  // transposes + h->bf16 + edge histogram
  prep_all<<<8732, 256, 0, stream>>>(W1f, W2f, W1p, W2p, w1f_t, w2f_t, w1p_t,
                                     w2p_t, h, h_bf, dst, deg_cnt);

  // CSR build
  scan_counts<<<1, 1024, 0, stream>>>(deg_cnt, rowstart);
  edge_fill<<<N_EDGES / 256, 256, 0, stream>>>(src, dst, rowstart, cursor, bucket);

  // aggregation (gather, XCD-swizzled) -> x in bf16
  gin_gather<<<N_NODES / 4, 256, 0, stream>>>(rowstart, bucket, h_bf, x_bf);

  // feat MLP + assign MLP + softmax, one launch (independent block ranges)
  feat_assign<<<256 + N_NODES / 128, 512, 0, stream>>>(
      x_bf, w1f_t, b1f, w2f_t, b2f, feat_bf,
      w1p_t, b1p, w2p_t, b2p, assign_bf);

  // adj @ assign via gather (standalone, high-occupancy)
  tmp_gather<<<N_NODES / 4, 256, 0, stream>>>(rowstart, bucket, assign_bf, tmp_bf);

  // outputs (MFMA)
  pool_adj_mfma<<<512, 256, 0, stream>>>(assign_bf, feat_bf, tmp_bf,
                                         out_adj, out_hpool);
}

// Round 15
// 201.463 us; speedup vs baseline: 1.4331x; 1.0761x over previous
//
#include <hip/hip_runtime.h>

#define N_NODES 32000
#define NPG     2000
#define NGRAPH  16
#define K_ASSIGN 1600
#define KPG     100
#define D_FEAT  128
#define N_EDGES 512000

typedef float f32x4 __attribute__((ext_vector_type(4)));
typedef __bf16 bf16x8 __attribute__((ext_vector_type(8)));

union FragU { unsigned u[4]; bf16x8 v; };

__device__ __forceinline__ float frelu(float v) { return fmaxf(v, 0.0f); }

__device__ __forceinline__ unsigned short f2bf(float f) {
  unsigned u = __float_as_uint(f);
  u += 0x7FFFu + ((u >> 16) & 1u);
  return (unsigned short)(u >> 16);
}
__device__ __forceinline__ float bfLO(unsigned v) { return __uint_as_float(v << 16); }
__device__ __forceinline__ float bfHI(unsigned v) { return __uint_as_float(v & 0xFFFF0000u); }

// ---------------------------------------------------------------------------
// prep_all: weight transposes (f32->bf16 [C][R]) + h->bf16 + edge histogram.
// ---------------------------------------------------------------------------
__global__ __launch_bounds__(256) void prep_all(
    const float* __restrict__ W1f, const float* __restrict__ W2f,
    const float* __restrict__ W1p, const float* __restrict__ W2p,
    unsigned short* __restrict__ o1, unsigned short* __restrict__ o2,
    unsigned short* __restrict__ o3, unsigned short* __restrict__ o4,
    const float* __restrict__ h, unsigned short* __restrict__ h_bf,
    const int* __restrict__ dst, int* __restrict__ cnt) {
  __shared__ float tile[32][33];
  int b = blockIdx.x;
  int t = threadIdx.x;
  if (b >= 6732) {  // edge histogram
    int e = (b - 6732) * 256 + t;
    if (e < N_EDGES) atomicAdd(&cnt[dst[e]], 1);
    return;
  }
  if (b >= 2732) {  // h -> bf16
    int i = (b - 2732) * 256 + t;  // float4 index
    float4 v = ((const float4*)h)[i];
    ushort4 o;
    o.x = f2bf(v.x); o.y = f2bf(v.y); o.z = f2bf(v.z); o.w = f2bf(v.w);
    ((ushort4*)h_bf)[i] = o;
    return;
  }
  const float* in;
  unsigned short* out;
  int R, C, rb;
  if (b < 16)       { in = W1f; out = o1; R = 128;  C = 128;  rb = b; }
  else if (b < 32)  { in = W2f; out = o2; R = 128;  C = 128;  rb = b - 16; }
  else if (b < 232) { in = W1p; out = o3; R = 128;  C = 1600; rb = b - 32; }
  else              { in = W2p; out = o4; R = 1600; C = 1600; rb = b - 232; }
  int ct = C >> 5;
  int bc = rb % ct, br = rb / ct;
  int r0 = br * 32, c0 = bc * 32;
#pragma unroll
  for (int i = 0; i < 4; i++) {
    int r = (t >> 5) + i * 8, c = t & 31;
    tile[r][c] = in[(size_t)(r0 + r) * C + c0 + c];
  }
  __syncthreads();
#pragma unroll
  for (int i = 0; i < 4; i++) {
    int c = (t >> 5) + i * 8, r = t & 31;
    out[(size_t)(c0 + c) * R + r0 + r] = f2bf(tile[r][c]);
  }
}

// ---------------------------------------------------------------------------
// CSR scan: 1024 threads, 32 counts each (1000 active).
// ---------------------------------------------------------------------------
__global__ __launch_bounds__(1024) void scan_counts(
    const int* __restrict__ cnt, int* __restrict__ rowstart) {
  __shared__ int sums[1024];
  int t = threadIdx.x;
  int base = t * 32;
  int s = 0;
  if (t < 1000)
    for (int i = 0; i < 32; i++) s += cnt[base + i];
  sums[t] = s;
  __syncthreads();
  for (int off = 1; off < 1024; off <<= 1) {
    int v = (t >= off) ? sums[t - off] : 0;
    __syncthreads();
    sums[t] += v;
    __syncthreads();
  }
  if (t < 1000) {
    int run = (t == 0) ? 0 : sums[t - 1];
    for (int i = 0; i < 32; i++) {
      rowstart[base + i] = run;
      run += cnt[base + i];
    }
  }
  if (t == 999) rowstart[32000] = sums[999];
}

__global__ __launch_bounds__(256) void edge_fill(
    const int* __restrict__ src, const int* __restrict__ dst,
    const int* __restrict__ rowstart, int* __restrict__ cursor,
    int* __restrict__ bucket) {
  int e = blockIdx.x * 256 + threadIdx.x;
  if (e < N_EDGES) {
    int d = dst[e];
    int pos = atomicAdd(&cursor[d], 1);
    bucket[rowstart[d] + pos] = src[e];
  }
}

// ---------------------------------------------------------------------------
// Gather aggregation + compute_x: x_bf[n] = bf16(h_bf[n] + mean h_bf[src]).
// XCD-chunked block swizzle (8000%8==0, bijective). No LDS, low VGPR.
// Self-row load issued BEFORE the loop so its latency hides under the gather.
// ---------------------------------------------------------------------------
__global__ __launch_bounds__(256) void gin_gather(
    const int* __restrict__ rowstart, const int* __restrict__ bucket,
    const unsigned short* __restrict__ h_bf, unsigned short* __restrict__ x_bf) {
  int bid = (int)(blockIdx.x & 7) * 1000 + (int)(blockIdx.x >> 3);
  int n = bid * 4 + (threadIdx.x >> 6);
  int lane = threadIdx.x & 63;
  int rs = rowstart[n], re = rowstart[n + 1];
  const unsigned* hb = (const unsigned*)h_bf;
  unsigned hv = hb[(size_t)n * 64 + lane];  // issued early
  float ax = 0.f, ay = 0.f;
  int e = rs;
  for (; e + 4 <= re; e += 4) {
    unsigned v0 = hb[(size_t)bucket[e] * 64 + lane];
    unsigned v1 = hb[(size_t)bucket[e + 1] * 64 + lane];
    unsigned v2 = hb[(size_t)bucket[e + 2] * 64 + lane];
    unsigned v3 = hb[(size_t)bucket[e + 3] * 64 + lane];
    ax += (bfLO(v0) + bfLO(v1)) + (bfLO(v2) + bfLO(v3));
    ay += (bfHI(v0) + bfHI(v1)) + (bfHI(v2) + bfHI(v3));
  }
  for (; e < re; e++) {
    unsigned v = hb[(size_t)bucket[e] * 64 + lane];
    ax += bfLO(v);
    ay += bfHI(v);
  }
  float invd = 1.0f / fmaxf((float)(re - rs), 1.0f);
  unsigned o = ((unsigned)f2bf(bfHI(hv) + ay * invd) << 16) |
               f2bf(bfLO(hv) + ax * invd);
  ((unsigned*)x_bf)[(size_t)n * 64 + lane] = o;
}

// ---------------------------------------------------------------------------
// MERGED feat + assign. Blocks [0,256): fused assign+softmax (128 rows each);
// blocks [256,506): feat 2-layer MLP (128 rows each). Both 512 threads.
// LDS-staged weights + double buffering (surviving structure after r12/r13
// falsified gather-fusion and direct-global variants).
// ---------------------------------------------------------------------------
#define FF_STR 136
#define FA_WS 136
#define FA_PS 72
#define FA_W1OFF 17408
#define FA_W2BASE 34816
#define FA_W2OFF 16128
__global__ __launch_bounds__(512) void feat_assign(
    const unsigned short* __restrict__ x_bf,
    const unsigned short* __restrict__ w1ft, const float* __restrict__ b1f,
    const unsigned short* __restrict__ w2ft, const float* __restrict__ b2f,
    unsigned short* __restrict__ feat_bf,
    const unsigned short* __restrict__ w1t, const float* __restrict__ b1p,
    const unsigned short* __restrict__ w2t, const float* __restrict__ b2p,
    unsigned short* __restrict__ assign_bf) {
  __shared__ __align__(16) unsigned char smem[69632];
  int t = threadIdx.x;
  int w = t >> 6, l = t & 63, lr = l & 15, lg = l >> 4;

  if (blockIdx.x >= 256) {
    // ---------------- feat path ----------------
    unsigned short* xa = (unsigned short*)smem;            // xt, then x1
    unsigned short* ws = (unsigned short*)(smem + 34816);  // W1, then W2
    size_t base = (size_t)(blockIdx.x - 256) * 128;

#pragma unroll
    for (int i = 0; i < 4; i++) {
      int fi = t + 512 * i;
      int r = fi >> 4, u8 = (fi & 15) * 8;
      *(uint4*)&xa[r * FF_STR + u8] = *(const uint4*)(x_bf + (base + r) * 128 + u8);
      *(uint4*)&ws[r * FF_STR + u8] = *(const uint4*)(w1ft + (size_t)r * 128 + u8);
    }
    __syncthreads();

    int myrow = 16 * w + lr;
    bf16x8 af[4];
#pragma unroll
    for (int kc = 0; kc < 4; kc++)
      af[kc] = *(bf16x8*)&xa[myrow * FF_STR + 32 * kc + 8 * lg];

    f32x4 p[8];
#pragma unroll
    for (int ntk = 0; ntk < 8; ntk++) {
      p[ntk] = (f32x4){0.f, 0.f, 0.f, 0.f};
      int c = 16 * ntk + lr;
#pragma unroll
      for (int kc = 0; kc < 4; kc++) {
        bf16x8 wf = *(bf16x8*)&ws[c * FF_STR + 32 * kc + 8 * lg];
        p[ntk] = __builtin_amdgcn_mfma_f32_16x16x32_bf16(wf, af[kc], p[ntk], 0, 0, 0);
      }
    }
    __syncthreads();

#pragma unroll
    for (int ntk = 0; ntk < 8; ntk++) {
      int kk0 = 16 * ntk + 4 * lg;
      float4 b1 = *(const float4*)(b1f + kk0);
      ushort4 pk;
      pk.x = f2bf(frelu(p[ntk][0] + b1.x));
      pk.y = f2bf(frelu(p[ntk][1] + b1.y));
      pk.z = f2bf(frelu(p[ntk][2] + b1.z));
      pk.w = f2bf(frelu(p[ntk][3] + b1.w));
      *(ushort4*)&xa[myrow * FF_STR + kk0] = pk;
    }
#pragma unroll
    for (int i = 0; i < 4; i++) {
      int fi = t + 512 * i;
      int r = fi >> 4, u8 = (fi & 15) * 8;
      *(uint4*)&ws[r * FF_STR + u8] = *(const uint4*)(w2ft + (size_t)r * 128 + u8);
    }
    __syncthreads();

    bf16x8 a2[4];
#pragma unroll
    for (int kc = 0; kc < 4; kc++)
      a2[kc] = *(bf16x8*)&xa[myrow * FF_STR + 32 * kc + 8 * lg];
#pragma unroll
    for (int nt = 0; nt < 8; nt++) {
      f32x4 q = (f32x4){0.f, 0.f, 0.f, 0.f};
      int c = 16 * nt + lr;
#pragma unroll
      for (int kc = 0; kc < 4; kc++) {
        bf16x8 wf = *(bf16x8*)&ws[c * FF_STR + 32 * kc + 8 * lg];
        q = __builtin_amdgcn_mfma_f32_16x16x32_bf16(wf, a2[kc], q, 0, 0, 0);
      }
      int c0 = 16 * nt + 4 * lg;
      float4 b2 = *(const float4*)(b2f + c0);
      ushort4 pk;
      pk.x = f2bf(frelu(q[0] + b2.x));
      pk.y = f2bf(frelu(q[1] + b2.y));
      pk.z = f2bf(frelu(q[2] + b2.z));
      pk.w = f2bf(frelu(q[3] + b2.w));
      *(ushort4*)&feat_bf[(base + myrow) * 128 + c0] = pk;
    }
    return;
  }

  // ---------------- assign path ----------------
  unsigned short* xt = (unsigned short*)smem;
  int g = blockIdx.x >> 4;
  int row0 = (blockIdx.x & 15) << 7;
  int n0 = g * NPG + row0;

#pragma unroll
  for (int i = 0; i < 4; i++) {
    int fi = t + 512 * i;
    int r = fi >> 4, u8 = (fi & 15) * 8;
    uint4 v = make_uint4(0, 0, 0, 0);
    if (row0 + r < NPG) v = *(const uint4*)(x_bf + (size_t)(n0 + r) * 128 + u8);
    *(uint4*)&xt[r * FA_WS + u8] = v;
  }
  __syncthreads();

  int rh = w >> 1, h = w & 1;

  bf16x8 af[2][4];
#pragma unroll
  for (int ct = 0; ct < 2; ct++)
#pragma unroll
    for (int kc = 0; kc < 4; kc++)
      af[ct][kc] =
          *(bf16x8*)&xt[(32 * rh + 16 * ct + lr) * FA_WS + 32 * kc + 8 * lg];
  __syncthreads();  // xt region becomes w1 buffers

  {
    unsigned short* w1s = (unsigned short*)smem;
    unsigned short* w2s = (unsigned short*)(smem + FA_W2BASE);
#pragma unroll
    for (int i = 0; i < 2; i++) {
      int fi = t + 512 * i;
      int c = fi >> 4, u8 = (fi & 15) * 8;
      *(uint4*)&w1s[c * FA_WS + u8] = *(const uint4*)(w1t + (size_t)c * 128 + u8);
    }
#pragma unroll
    for (int i = 0; i < 2; i++) {
      int fi = t + 512 * i;
      if (fi < 896) {
        int c = fi >> 3, u8 = (fi & 7) * 8;
        uint4 v = make_uint4(0, 0, 0, 0);
        if (c < KPG)
          v = *(const uint4*)(w2t + (size_t)(g * KPG + c) * K_ASSIGN + u8);
        *(uint4*)&w2s[c * FA_PS + u8] = v;
      }
    }
  }
  __syncthreads();

  f32x4 acc[7][2];
#pragma unroll
  for (int i = 0; i < 7; i++) {
    acc[i][0] = (f32x4){0.f, 0.f, 0.f, 0.f};
    acc[i][1] = (f32x4){0.f, 0.f, 0.f, 0.f};
  }

  for (int cch = 0; cch < 25; cch++) {
    int cur = cch & 1;
    int k0 = cch * 64;
    const unsigned short* w1c = (const unsigned short*)(smem + cur * FA_W1OFF);
    const unsigned short* w2c =
        (const unsigned short*)(smem + FA_W2BASE + cur * FA_W2OFF);
    bool pf = (cch < 24);
    uint4 rA[2], rB[2];
    if (pf) {
      int k1 = k0 + 64;
#pragma unroll
      for (int i = 0; i < 2; i++) {
        int fi = t + 512 * i;
        int c = fi >> 4, u8 = (fi & 15) * 8;
        rA[i] = *(const uint4*)(w1t + (size_t)(k1 + c) * 128 + u8);
      }
#pragma unroll
      for (int i = 0; i < 2; i++) {
        int fi = t + 512 * i;
        rB[i] = make_uint4(0, 0, 0, 0);
        if (fi < 896) {
          int c = fi >> 3, u8 = (fi & 7) * 8;
          if (c < KPG)
            rB[i] = *(const uint4*)(w2t + (size_t)(g * KPG + c) * K_ASSIGN +
                                    k1 + u8);
        }
      }
    }

    f32x4 p[2][2];
    __builtin_amdgcn_s_setprio(1);
#pragma unroll
    for (int nt2 = 0; nt2 < 2; nt2++) {
      p[nt2][0] = (f32x4){0.f, 0.f, 0.f, 0.f};
      p[nt2][1] = (f32x4){0.f, 0.f, 0.f, 0.f};
      int nt = 2 * h + nt2;
#pragma unroll
      for (int kc = 0; kc < 4; kc++) {
        bf16x8 wf = *(bf16x8*)&w1c[(16 * nt + lr) * FA_WS + 32 * kc + 8 * lg];
        p[nt2][0] = __builtin_amdgcn_mfma_f32_16x16x32_bf16(wf, af[0][kc],
                                                            p[nt2][0], 0, 0, 0);
        p[nt2][1] = __builtin_amdgcn_mfma_f32_16x16x32_bf16(wf, af[1][kc],
                                                            p[nt2][1], 0, 0, 0);
      }
    }
    __builtin_amdgcn_s_setprio(0);
    unsigned q[2][2][2];
#pragma unroll
    for (int nt2 = 0; nt2 < 2; nt2++) {
      int kkb = k0 + 16 * (2 * h + nt2) + 4 * lg;
      float4 b1 = *(const float4*)(b1p + kkb);
#pragma unroll
      for (int ct = 0; ct < 2; ct++) {
        float r0 = frelu(p[nt2][ct][0] + b1.x);
        float r1 = frelu(p[nt2][ct][1] + b1.y);
        float r2 = frelu(p[nt2][ct][2] + b1.z);
        float r3 = frelu(p[nt2][ct][3] + b1.w);
        q[nt2][ct][0] = ((unsigned)f2bf(r1) << 16) | f2bf(r0);
        q[nt2][ct][1] = ((unsigned)f2bf(r3) << 16) | f2bf(r2);
      }
    }
    int sA = lr + 32 * (lg & 1);
    int sB = sA + 16;
    bool hi = (lg >= 2);
    FragU pa[2];
#pragma unroll
    for (int ct = 0; ct < 2; ct++) {
      unsigned a0 = (unsigned)__shfl((int)q[0][ct][0], sA, 64);
      unsigned b0 = (unsigned)__shfl((int)q[1][ct][0], sA, 64);
      unsigned a1 = (unsigned)__shfl((int)q[0][ct][1], sA, 64);
      unsigned b1u = (unsigned)__shfl((int)q[1][ct][1], sA, 64);
      unsigned a2 = (unsigned)__shfl((int)q[0][ct][0], sB, 64);
      unsigned b2u = (unsigned)__shfl((int)q[1][ct][0], sB, 64);
      unsigned a3 = (unsigned)__shfl((int)q[0][ct][1], sB, 64);
      unsigned b3u = (unsigned)__shfl((int)q[1][ct][1], sB, 64);
      pa[ct].u[0] = hi ? b0 : a0;
      pa[ct].u[1] = hi ? b1u : a1;
      pa[ct].u[2] = hi ? b2u : a2;
      pa[ct].u[3] = hi ? b3u : a3;
    }
    // prefetched chunk -> alternate buffers before phase-2 (drains under MFMA)
    if (pf) {
      unsigned short* w1n = (unsigned short*)(smem + (cur ^ 1) * FA_W1OFF);
      unsigned short* w2n =
          (unsigned short*)(smem + FA_W2BASE + (cur ^ 1) * FA_W2OFF);
#pragma unroll
      for (int i = 0; i < 2; i++) {
        int fi = t + 512 * i;
        int c = fi >> 4, u8 = (fi & 15) * 8;
        *(uint4*)&w1n[c * FA_WS + u8] = rA[i];
      }
#pragma unroll
      for (int i = 0; i < 2; i++) {
        int fi = t + 512 * i;
        if (fi < 896) {
          int c = fi >> 3, u8 = (fi & 7) * 8;
          *(uint4*)&w2n[c * FA_PS + u8] = rB[i];
        }
      }
    }
    __builtin_amdgcn_s_setprio(1);
#pragma unroll
    for (int ct2 = 0; ct2 < 7; ct2++) {
      bf16x8 wv = *(bf16x8*)&w2c[(16 * ct2 + lr) * FA_PS + 32 * h + 8 * lg];
      acc[ct2][0] = __builtin_amdgcn_mfma_f32_16x16x32_bf16(wv, pa[0].v,
                                                            acc[ct2][0], 0, 0, 0);
      acc[ct2][1] = __builtin_amdgcn_mfma_f32_16x16x32_bf16(wv, pa[1].v,
                                                            acc[ct2][1], 0, 0, 0);
    }
    __builtin_amdgcn_s_setprio(0);
    __syncthreads();
  }

  // cross-h reduction
  float* red = (float*)smem;
  if (h == 1) {
#pragma unroll
    for (int ct2 = 0; ct2 < 7; ct2++)
#pragma unroll
      for (int ct = 0; ct < 2; ct++)
        *(f32x4*)&red[((rh * 14 + ct2 * 2 + ct) * 64 + l) * 4] = acc[ct2][ct];
  }
  __syncthreads();
  if (h == 0) {
#pragma unroll
    for (int ct2 = 0; ct2 < 7; ct2++)
#pragma unroll
      for (int ct = 0; ct < 2; ct++)
        acc[ct2][ct] += *(f32x4*)&red[((rh * 14 + ct2 * 2 + ct) * 64 + l) * 4];

    // fused masked softmax
#pragma unroll
    for (int ct = 0; ct < 2; ct++) {
      int xrow = row0 + 32 * rh + 16 * ct + lr;
      float v[7][4];
      float m = 0.0f;
#pragma unroll
      for (int ct2 = 0; ct2 < 7; ct2++) {
        int col0 = 16 * ct2 + 4 * lg;
        if (col0 < KPG) {
          float4 b2 = *(const float4*)(b2p + g * KPG + col0);
          v[ct2][0] = frelu(acc[ct2][ct][0] + b2.x);
          v[ct2][1] = frelu(acc[ct2][ct][1] + b2.y);
          v[ct2][2] = frelu(acc[ct2][ct][2] + b2.z);
          v[ct2][3] = frelu(acc[ct2][ct][3] + b2.w);
          m = fmaxf(m, fmaxf(fmaxf(v[ct2][0], v[ct2][1]),
                             fmaxf(v[ct2][2], v[ct2][3])));
        }
      }
      m = fmaxf(m, __shfl_xor(m, 16, 64));
      m = fmaxf(m, __shfl_xor(m, 32, 64));
      float s = 0.0f;
#pragma unroll
      for (int ct2 = 0; ct2 < 7; ct2++) {
        int col0 = 16 * ct2 + 4 * lg;
        if (col0 < KPG) {
          v[ct2][0] = expf(v[ct2][0] - m);
          v[ct2][1] = expf(v[ct2][1] - m);
          v[ct2][2] = expf(v[ct2][2] - m);
          v[ct2][3] = expf(v[ct2][3] - m);
          s += (v[ct2][0] + v[ct2][1]) + (v[ct2][2] + v[ct2][3]);
        }
      }
      s += __shfl_xor(s, 16, 64);
      s += __shfl_xor(s, 32, 64);
      float denom = s + (float)(K_ASSIGN - KPG) * expf(-m);
      float scale = 1.0f / (s + 1e-13f * denom);
      if (xrow < NPG) {
#pragma unroll
        for (int ct2 = 0; ct2 < 7; ct2++) {
          int col0 = 16 * ct2 + 4 * lg;
          if (col0 < KPG) {
            ushort4 pk;
            pk.x = f2bf(v[ct2][0] * scale);
            pk.y = f2bf(v[ct2][1] * scale);
            pk.z = f2bf(v[ct2][2] * scale);
            pk.w = f2bf(v[ct2][3] * scale);
            *(ushort4*)(assign_bf + ((size_t)g * NPG + xrow) * KPG + col0) = pk;
          }
        }
      }
    }
  }
}

// ---------------------------------------------------------------------------
// tmp_bf[n] = sum_{e->n} assign_bf[src_e]. Standalone: no LDS, low VGPR ->
// high occupancy (latency-bound gather needs TLP).
// ---------------------------------------------------------------------------
__global__ __launch_bounds__(256) void tmp_gather(
    const int* __restrict__ rowstart, const int* __restrict__ bucket,
    const unsigned short* __restrict__ assign_bf, unsigned short* __restrict__ tmp_bf) {
  int bid = (int)(blockIdx.x & 7) * 1000 + (int)(blockIdx.x >> 3);
  int n = bid * 4 + (threadIdx.x >> 6);
  int lane = threadIdx.x & 63;
  if (lane >= 50) return;
  int rs = rowstart[n], re = rowstart[n + 1];
  const unsigned* ab = (const unsigned*)assign_bf;
  float ax = 0.f, ay = 0.f;
  int e = rs;
  for (; e + 4 <= re; e += 4) {
    unsigned v0 = ab[(size_t)bucket[e] * 50 + lane];
    unsigned v1 = ab[(size_t)bucket[e + 1] * 50 + lane];
    unsigned v2 = ab[(size_t)bucket[e + 2] * 50 + lane];
    unsigned v3 = ab[(size_t)bucket[e + 3] * 50 + lane];
    ax += (bfLO(v0) + bfLO(v1)) + (bfLO(v2) + bfLO(v3));
    ay += (bfHI(v0) + bfHI(v1)) + (bfHI(v2) + bfHI(v3));
  }
  for (; e < re; e++) {
    unsigned v = ab[(size_t)bucket[e] * 50 + lane];
    ax += bfLO(v);
    ay += bfHI(v);
  }
  unsigned o = ((unsigned)f2bf(ay) << 16) | f2bf(ax);
  ((unsigned*)tmp_bf)[(size_t)n * 50 + lane] = o;
}

// ---------------------------------------------------------------------------
// pool (blocks 0..127) + adj (blocks 128..255), MFMA over K=n.
// PA_CHN=250 (2000 = 8 x 250 exactly): each output element accumulated by
// 8 blocks instead of 16 -> atomic f32 volume halves vs PA_CHN=128.
// ---------------------------------------------------------------------------
#define PA_STR 72
#define PA_CHN 250
__global__ __launch_bounds__(256) void pool_adj_mfma(
    const unsigned short* __restrict__ assign_bf,
    const unsigned short* __restrict__ feat_bf,
    const unsigned short* __restrict__ tmp_bf,
    float* __restrict__ out_adj, float* __restrict__ out_hpool) {
  __shared__ __align__(16) unsigned short as[112 * PA_STR];
  __shared__ __align__(16) unsigned short bs[128 * PA_STR];
  bool is_pool = blockIdx.x < 128;
  int bb = is_pool ? blockIdx.x : blockIdx.x - 128;
  int g = bb >> 3, ch = bb & 7;
  int nbase = ch * PA_CHN;
  int lim = PA_CHN;  // 2000 = 8*250 exact
  int t = threadIdx.x;
  int w = t >> 6, l = t & 63, lr = l & 15, lg = l >> 4;
  const unsigned* au = (const unsigned*)assign_bf;
  const unsigned* fu = (const unsigned*)feat_bf;
  const unsigned* tu = (const unsigned*)tmp_bf;

  for (int i = t; i < 12 * PA_STR; i += 256) as[100 * PA_STR + i] = 0;
  for (int i = t; i < 28 * PA_STR; i += 256) bs[100 * PA_STR + i] = 0;

  f32x4 acc[7][2];
#pragma unroll
  for (int i = 0; i < 7; i++) {
    acc[i][0] = (f32x4){0.f, 0.f, 0.f, 0.f};
    acc[i][1] = (f32x4){0.f, 0.f, 0.f, 0.f};
  }

  for (int kt = 0; kt < 4; kt++) {  // 4 x 64 = 256 >= 250; tail zero-filled
    int nt0 = kt * 64;
    __syncthreads();
#pragma unroll
    for (int i = 0; i < 13; i++) {
      int idx = t + 256 * i;
      if (idx < 3200) {
        int r = idx / 50, cu = idx % 50;
        int nl = nt0 + r;
        unsigned v = 0;
        if (nl < lim) v = au[(size_t)(g * NPG + nbase + nl) * 50 + cu];
        as[(2 * cu) * PA_STR + r] = (unsigned short)(v & 0xFFFFu);
        as[(2 * cu + 1) * PA_STR + r] = (unsigned short)(v >> 16);
      }
    }
    if (is_pool) {
#pragma unroll
      for (int i = 0; i < 16; i++) {
        int idx = t + 256 * i;
        int r = idx >> 6, cu = idx & 63;
        int nl = nt0 + r;
        unsigned v = 0;
        if (nl < lim) v = fu[(size_t)(g * NPG + nbase + nl) * 64 + cu];
        bs[(2 * cu) * PA_STR + r] = (unsigned short)(v & 0xFFFFu);
        bs[(2 * cu + 1) * PA_STR + r] = (unsigned short)(v >> 16);
      }
    } else {
#pragma unroll
      for (int i = 0; i < 13; i++) {
        int idx = t + 256 * i;
        if (idx < 3200) {
          int r = idx / 50, cu = idx % 50;
          int nl = nt0 + r;
          unsigned v = 0;
          if (nl < lim) v = tu[(size_t)(g * NPG + nbase + nl) * 50 + cu];
          bs[(2 * cu) * PA_STR + r] = (unsigned short)(v & 0xFFFFu);
          bs[(2 * cu + 1) * PA_STR + r] = (unsigned short)(v >> 16);
        }
      }
    }
    __syncthreads();
#pragma unroll
    for (int kc = 0; kc < 2; kc++) {
      bf16x8 afr[7];
#pragma unroll
      for (int mt = 0; mt < 7; mt++)
        afr[mt] = *(bf16x8*)&as[(16 * mt + lr) * PA_STR + 32 * kc + 8 * lg];
#pragma unroll
      for (int nt2 = 0; nt2 < 2; nt2++) {
        int nt = 2 * w + nt2;
        bf16x8 bfr = *(bf16x8*)&bs[(16 * nt + lr) * PA_STR + 32 * kc + 8 * lg];
#pragma unroll
        for (int mt = 0; mt < 7; mt++)
          acc[mt][nt2] =
              __builtin_amdgcn_mfma_f32_16x16x32_bf16(afr[mt], bfr, acc[mt][nt2], 0, 0, 0);
      }
    }
  }

  if (is_pool) {
#pragma unroll
    for (int mt = 0; mt < 7; mt++)
#pragma unroll
      for (int nt2 = 0; nt2 < 2; nt2++) {
        int nt = 2 * w + nt2;
#pragma unroll
        for (int r = 0; r < 4; r++) {
          int m = 16 * mt + 4 * lg + r;
          if (m < KPG)
            atomicAdd(out_hpool + ((size_t)g * KPG + m) * 128 + 16 * nt + lr,
                      acc[mt][nt2][r]);
        }
      }
  } else {
#pragma unroll
    for (int mt = 0; mt < 7; mt++)
#pragma unroll
      for (int nt2 = 0; nt2 < 2; nt2++) {
        int nt = 2 * w + nt2;
        if (nt < 7) {
          int k2 = 16 * nt + lr;
          if (k2 < KPG) {
#pragma unroll
            for (int r = 0; r < 4; r++) {
              int m = 16 * mt + 4 * lg + r;
              if (m < KPG)
                atomicAdd(out_adj + ((size_t)g * KPG + m) * K_ASSIGN + g * KPG + k2,
                          acc[mt][nt2][r]);
            }
          }
        }
      }
  }
}

extern "C" void kernel_launch(void* const* d_in, const int* in_sizes, int n_in,
                              void* d_out, int out_size, void* d_ws,
                              size_t ws_size, hipStream_t stream) {
  (void)in_sizes; (void)n_in; (void)ws_size;
  const float* h   = (const float*)d_in[0];
  const int*   src = (const int*)d_in[1];
  const int*   dst = (const int*)d_in[2];
  const float* W1f = (const float*)d_in[3];
  const float* b1f = (const float*)d_in[4];
  const float* W2f = (const float*)d_in[5];
  const float* b2f = (const float*)d_in[6];
  const float* W1p = (const float*)d_in[7];
  const float* b1p = (const float*)d_in[8];
  const float* W2p = (const float*)d_in[9];
  const float* b2p = (const float*)d_in[10];

  float* out_adj   = (float*)d_out;
  float* out_hpool = out_adj + (size_t)K_ASSIGN * K_ASSIGN;

  char* ws = (char*)d_ws;
  int* deg_cnt  = (int*)(ws + 0);            //   128,000
  int* cursor   = (int*)(ws + 128000);       //   128,000
  int* rowstart = (int*)(ws + 256000);       //   128,032
  int* bucket   = (int*)(ws + 384032);       // 2,048,000
  unsigned short* h_bf      = (unsigned short*)(ws + 2432032);   // 8,192,000
  unsigned short* x_bf      = (unsigned short*)(ws + 10624032);  // 8,192,000
  unsigned short* feat_bf   = (unsigned short*)(ws + 18816032);  // 8,192,000
  unsigned short* assign_bf = (unsigned short*)(ws + 27008032);  // 6,400,000
  unsigned short* tmp_bf    = (unsigned short*)(ws + 33408032);  // 6,400,000
  unsigned short* w1f_t     = (unsigned short*)(ws + 39808032);  //    32,768
  unsigned short* w2f_t     = (unsigned short*)(ws + 39840800);  //    32,768
  unsigned short* w1p_t     = (unsigned short*)(ws + 39873568);  //   409,600
  unsigned short* w2p_t     = (unsigned short*)(ws + 40283168);  // 5,120,000

  hipMemsetAsync(deg_cnt, 0, 256000, stream);  // deg_cnt + cursor
  hipMemsetAsync(d_out, 0, (size_t)out_size * sizeof(float), stream);

  // transposes + h->bf16 + edge histogram
  prep_all<<<8732, 256, 0, stream>>>(W1f, W2f, W1p, W2p, w1f_t, w2f_t, w1p_t,
                                     w2p_t, h, h_bf, dst, deg_cnt);

  // CSR build
  scan_counts<<<1, 1024, 0, stream>>>(deg_cnt, rowstart);
  edge_fill<<<N_EDGES / 256, 256, 0, stream>>>(src, dst, rowstart, cursor, bucket);

  // aggregation (gather, XCD-swizzled) -> x in bf16
  gin_gather<<<N_NODES / 4, 256, 0, stream>>>(rowstart, bucket, h_bf, x_bf);

  // feat MLP + assign MLP + softmax, one launch (independent block ranges)
  feat_assign<<<256 + N_NODES / 128, 512, 0, stream>>>(
      x_bf, w1f_t, b1f, w2f_t, b2f, feat_bf,
      w1p_t, b1p, w2p_t, b2p, assign_bf);

  // adj @ assign via gather (standalone, high-occupancy)
  tmp_gather<<<N_NODES / 4, 256, 0, stream>>>(rowstart, bucket, assign_bf, tmp_bf);

  // outputs (MFMA, 250-row chunks -> half the atomic volume)
  pool_adj_mfma<<<256, 256, 0, stream>>>(assign_bf, feat_bf, tmp_bf,
                                         out_adj, out_hpool);
}

// Round 16
// 199.661 us; speedup vs baseline: 1.4460x; 1.0090x over previous
//
#include <hip/hip_runtime.h>

#define N_NODES 32000
#define NPG     2000
#define NGRAPH  16
#define K_ASSIGN 1600
#define KPG     100
#define D_FEAT  128
#define N_EDGES 512000

typedef float f32x4 __attribute__((ext_vector_type(4)));
typedef __bf16 bf16x8 __attribute__((ext_vector_type(8)));

union FragU { unsigned u[4]; bf16x8 v; };

__device__ __forceinline__ float frelu(float v) { return fmaxf(v, 0.0f); }

__device__ __forceinline__ unsigned short f2bf(float f) {
  unsigned u = __float_as_uint(f);
  u += 0x7FFFu + ((u >> 16) & 1u);
  return (unsigned short)(u >> 16);
}
__device__ __forceinline__ float bfLO(unsigned v) { return __uint_as_float(v << 16); }
__device__ __forceinline__ float bfHI(unsigned v) { return __uint_as_float(v & 0xFFFF0000u); }

// ---------------------------------------------------------------------------
// K1: edge histogram (blocks [0,2000)) + h->bf16 (blocks [2000,6000)).
// Only what scan/gin need — transposes moved off this critical-path stage.
// ---------------------------------------------------------------------------
__global__ __launch_bounds__(256) void hist_hbf(
    const int* __restrict__ dst, int* __restrict__ cnt,
    const float* __restrict__ h, unsigned short* __restrict__ h_bf) {
  int b = blockIdx.x;
  int t = threadIdx.x;
  if (b < 2000) {
    int e = b * 256 + t;
    if (e < N_EDGES) atomicAdd(&cnt[dst[e]], 1);
    return;
  }
  int i = (b - 2000) * 256 + t;  // float4 index
  float4 v = ((const float4*)h)[i];
  ushort4 o;
  o.x = f2bf(v.x); o.y = f2bf(v.y); o.z = f2bf(v.z); o.w = f2bf(v.w);
  ((ushort4*)h_bf)[i] = o;
}

// ---------------------------------------------------------------------------
// CSR scan: 1024 threads, 32 counts each (1000 active).
// ---------------------------------------------------------------------------
__global__ __launch_bounds__(1024) void scan_counts(
    const int* __restrict__ cnt, int* __restrict__ rowstart) {
  __shared__ int sums[1024];
  int t = threadIdx.x;
  int base = t * 32;
  int s = 0;
  if (t < 1000)
    for (int i = 0; i < 32; i++) s += cnt[base + i];
  sums[t] = s;
  __syncthreads();
  for (int off = 1; off < 1024; off <<= 1) {
    int v = (t >= off) ? sums[t - off] : 0;
    __syncthreads();
    sums[t] += v;
    __syncthreads();
  }
  if (t < 1000) {
    int run = (t == 0) ? 0 : sums[t - 1];
    for (int i = 0; i < 32; i++) {
      rowstart[base + i] = run;
      run += cnt[base + i];
    }
  }
  if (t == 999) rowstart[32000] = sums[999];
}

// ---------------------------------------------------------------------------
// K3: edge_fill (blocks [0,2000)) + weight transposes (blocks [2000,4732)).
// Transposes (needed only by feat_assign, later) ride with the atomic-bound
// fill blocks — compatible low-resource profiles.
// ---------------------------------------------------------------------------
__global__ __launch_bounds__(256) void fill_transpose(
    const int* __restrict__ src, const int* __restrict__ dst,
    const int* __restrict__ rowstart, int* __restrict__ cursor,
    int* __restrict__ bucket,
    const float* __restrict__ W1f, const float* __restrict__ W2f,
    const float* __restrict__ W1p, const float* __restrict__ W2p,
    unsigned short* __restrict__ o1, unsigned short* __restrict__ o2,
    unsigned short* __restrict__ o3, unsigned short* __restrict__ o4) {
  __shared__ float tile[32][33];
  int b = blockIdx.x;
  int t = threadIdx.x;
  if (b < 2000) {
    int e = b * 256 + t;
    if (e < N_EDGES) {
      int d = dst[e];
      int pos = atomicAdd(&cursor[d], 1);
      bucket[rowstart[d] + pos] = src[e];
    }
    return;
  }
  int tb = b - 2000;
  const float* in;
  unsigned short* out;
  int R, C, rb;
  if (tb < 16)       { in = W1f; out = o1; R = 128;  C = 128;  rb = tb; }
  else if (tb < 32)  { in = W2f; out = o2; R = 128;  C = 128;  rb = tb - 16; }
  else if (tb < 232) { in = W1p; out = o3; R = 128;  C = 1600; rb = tb - 32; }
  else               { in = W2p; out = o4; R = 1600; C = 1600; rb = tb - 232; }
  int ct = C >> 5;
  int bc = rb % ct, br = rb / ct;
  int r0 = br * 32, c0 = bc * 32;
#pragma unroll
  for (int i = 0; i < 4; i++) {
    int r = (t >> 5) + i * 8, c = t & 31;
    tile[r][c] = in[(size_t)(r0 + r) * C + c0 + c];
  }
  __syncthreads();
#pragma unroll
  for (int i = 0; i < 4; i++) {
    int c = (t >> 5) + i * 8, r = t & 31;
    out[(size_t)(c0 + c) * R + r0 + r] = f2bf(tile[r][c]);
  }
}

// ---------------------------------------------------------------------------
// Gather aggregation + compute_x: x_bf[n] = bf16(h_bf[n] + mean h_bf[src]).
// XCD-chunked block swizzle; self-row load issued early.
// ---------------------------------------------------------------------------
__global__ __launch_bounds__(256) void gin_gather(
    const int* __restrict__ rowstart, const int* __restrict__ bucket,
    const unsigned short* __restrict__ h_bf, unsigned short* __restrict__ x_bf) {
  int bid = (int)(blockIdx.x & 7) * 1000 + (int)(blockIdx.x >> 3);
  int n = bid * 4 + (threadIdx.x >> 6);
  int lane = threadIdx.x & 63;
  int rs = rowstart[n], re = rowstart[n + 1];
  const unsigned* hb = (const unsigned*)h_bf;
  unsigned hv = hb[(size_t)n * 64 + lane];  // issued early
  float ax = 0.f, ay = 0.f;
  int e = rs;
  for (; e + 4 <= re; e += 4) {
    unsigned v0 = hb[(size_t)bucket[e] * 64 + lane];
    unsigned v1 = hb[(size_t)bucket[e + 1] * 64 + lane];
    unsigned v2 = hb[(size_t)bucket[e + 2] * 64 + lane];
    unsigned v3 = hb[(size_t)bucket[e + 3] * 64 + lane];
    ax += (bfLO(v0) + bfLO(v1)) + (bfLO(v2) + bfLO(v3));
    ay += (bfHI(v0) + bfHI(v1)) + (bfHI(v2) + bfHI(v3));
  }
  for (; e < re; e++) {
    unsigned v = hb[(size_t)bucket[e] * 64 + lane];
    ax += bfLO(v);
    ay += bfHI(v);
  }
  float invd = 1.0f / fmaxf((float)(re - rs), 1.0f);
  unsigned o = ((unsigned)f2bf(bfHI(hv) + ay * invd) << 16) |
               f2bf(bfLO(hv) + ax * invd);
  ((unsigned*)x_bf)[(size_t)n * 64 + lane] = o;
}

// ---------------------------------------------------------------------------
// MERGED feat + assign. Blocks [0,256): fused assign+softmax (128 rows each);
// blocks [256,506): feat 2-layer MLP (128 rows each). Both 512 threads.
// ---------------------------------------------------------------------------
#define FF_STR 136
#define FA_WS 136
#define FA_PS 72
#define FA_W1OFF 17408
#define FA_W2BASE 34816
#define FA_W2OFF 16128
__global__ __launch_bounds__(512) void feat_assign(
    const unsigned short* __restrict__ x_bf,
    const unsigned short* __restrict__ w1ft, const float* __restrict__ b1f,
    const unsigned short* __restrict__ w2ft, const float* __restrict__ b2f,
    unsigned short* __restrict__ feat_bf,
    const unsigned short* __restrict__ w1t, const float* __restrict__ b1p,
    const unsigned short* __restrict__ w2t, const float* __restrict__ b2p,
    unsigned short* __restrict__ assign_bf) {
  __shared__ __align__(16) unsigned char smem[69632];
  int t = threadIdx.x;
  int w = t >> 6, l = t & 63, lr = l & 15, lg = l >> 4;

  if (blockIdx.x >= 256) {
    // ---------------- feat path ----------------
    unsigned short* xa = (unsigned short*)smem;            // xt, then x1
    unsigned short* ws = (unsigned short*)(smem + 34816);  // W1, then W2
    size_t base = (size_t)(blockIdx.x - 256) * 128;

#pragma unroll
    for (int i = 0; i < 4; i++) {
      int fi = t + 512 * i;
      int r = fi >> 4, u8 = (fi & 15) * 8;
      *(uint4*)&xa[r * FF_STR + u8] = *(const uint4*)(x_bf + (base + r) * 128 + u8);
      *(uint4*)&ws[r * FF_STR + u8] = *(const uint4*)(w1ft + (size_t)r * 128 + u8);
    }
    __syncthreads();

    int myrow = 16 * w + lr;
    bf16x8 af[4];
#pragma unroll
    for (int kc = 0; kc < 4; kc++)
      af[kc] = *(bf16x8*)&xa[myrow * FF_STR + 32 * kc + 8 * lg];

    f32x4 p[8];
#pragma unroll
    for (int ntk = 0; ntk < 8; ntk++) {
      p[ntk] = (f32x4){0.f, 0.f, 0.f, 0.f};
      int c = 16 * ntk + lr;
#pragma unroll
      for (int kc = 0; kc < 4; kc++) {
        bf16x8 wf = *(bf16x8*)&ws[c * FF_STR + 32 * kc + 8 * lg];
        p[ntk] = __builtin_amdgcn_mfma_f32_16x16x32_bf16(wf, af[kc], p[ntk], 0, 0, 0);
      }
    }
    __syncthreads();

#pragma unroll
    for (int ntk = 0; ntk < 8; ntk++) {
      int kk0 = 16 * ntk + 4 * lg;
      float4 b1 = *(const float4*)(b1f + kk0);
      ushort4 pk;
      pk.x = f2bf(frelu(p[ntk][0] + b1.x));
      pk.y = f2bf(frelu(p[ntk][1] + b1.y));
      pk.z = f2bf(frelu(p[ntk][2] + b1.z));
      pk.w = f2bf(frelu(p[ntk][3] + b1.w));
      *(ushort4*)&xa[myrow * FF_STR + kk0] = pk;
    }
#pragma unroll
    for (int i = 0; i < 4; i++) {
      int fi = t + 512 * i;
      int r = fi >> 4, u8 = (fi & 15) * 8;
      *(uint4*)&ws[r * FF_STR + u8] = *(const uint4*)(w2ft + (size_t)r * 128 + u8);
    }
    __syncthreads();

    bf16x8 a2[4];
#pragma unroll
    for (int kc = 0; kc < 4; kc++)
      a2[kc] = *(bf16x8*)&xa[myrow * FF_STR + 32 * kc + 8 * lg];
#pragma unroll
    for (int nt = 0; nt < 8; nt++) {
      f32x4 q = (f32x4){0.f, 0.f, 0.f, 0.f};
      int c = 16 * nt + lr;
#pragma unroll
      for (int kc = 0; kc < 4; kc++) {
        bf16x8 wf = *(bf16x8*)&ws[c * FF_STR + 32 * kc + 8 * lg];
        q = __builtin_amdgcn_mfma_f32_16x16x32_bf16(wf, a2[kc], q, 0, 0, 0);
      }
      int c0 = 16 * nt + 4 * lg;
      float4 b2 = *(const float4*)(b2f + c0);
      ushort4 pk;
      pk.x = f2bf(frelu(q[0] + b2.x));
      pk.y = f2bf(frelu(q[1] + b2.y));
      pk.z = f2bf(frelu(q[2] + b2.z));
      pk.w = f2bf(frelu(q[3] + b2.w));
      *(ushort4*)&feat_bf[(base + myrow) * 128 + c0] = pk;
    }
    return;
  }

  // ---------------- assign path ----------------
  unsigned short* xt = (unsigned short*)smem;
  int g = blockIdx.x >> 4;
  int row0 = (blockIdx.x & 15) << 7;
  int n0 = g * NPG + row0;

#pragma unroll
  for (int i = 0; i < 4; i++) {
    int fi = t + 512 * i;
    int r = fi >> 4, u8 = (fi & 15) * 8;
    uint4 v = make_uint4(0, 0, 0, 0);
    if (row0 + r < NPG) v = *(const uint4*)(x_bf + (size_t)(n0 + r) * 128 + u8);
    *(uint4*)&xt[r * FA_WS + u8] = v;
  }
  __syncthreads();

  int rh = w >> 1, h = w & 1;

  bf16x8 af[2][4];
#pragma unroll
  for (int ct = 0; ct < 2; ct++)
#pragma unroll
    for (int kc = 0; kc < 4; kc++)
      af[ct][kc] =
          *(bf16x8*)&xt[(32 * rh + 16 * ct + lr) * FA_WS + 32 * kc + 8 * lg];
  __syncthreads();  // xt region becomes w1 buffers

  {
    unsigned short* w1s = (unsigned short*)smem;
    unsigned short* w2s = (unsigned short*)(smem + FA_W2BASE);
#pragma unroll
    for (int i = 0; i < 2; i++) {
      int fi = t + 512 * i;
      int c = fi >> 4, u8 = (fi & 15) * 8;
      *(uint4*)&w1s[c * FA_WS + u8] = *(const uint4*)(w1t + (size_t)c * 128 + u8);
    }
#pragma unroll
    for (int i = 0; i < 2; i++) {
      int fi = t + 512 * i;
      if (fi < 896) {
        int c = fi >> 3, u8 = (fi & 7) * 8;
        uint4 v = make_uint4(0, 0, 0, 0);
        if (c < KPG)
          v = *(const uint4*)(w2t + (size_t)(g * KPG + c) * K_ASSIGN + u8);
        *(uint4*)&w2s[c * FA_PS + u8] = v;
      }
    }
  }
  __syncthreads();

  f32x4 acc[7][2];
#pragma unroll
  for (int i = 0; i < 7; i++) {
    acc[i][0] = (f32x4){0.f, 0.f, 0.f, 0.f};
    acc[i][1] = (f32x4){0.f, 0.f, 0.f, 0.f};
  }

  for (int cch = 0; cch < 25; cch++) {
    int cur = cch & 1;
    int k0 = cch * 64;
    const unsigned short* w1c = (const unsigned short*)(smem + cur * FA_W1OFF);
    const unsigned short* w2c =
        (const unsigned short*)(smem + FA_W2BASE + cur * FA_W2OFF);
    bool pf = (cch < 24);
    uint4 rA[2], rB[2];
    if (pf) {
      int k1 = k0 + 64;
#pragma unroll
      for (int i = 0; i < 2; i++) {
        int fi = t + 512 * i;
        int c = fi >> 4, u8 = (fi & 15) * 8;
        rA[i] = *(const uint4*)(w1t + (size_t)(k1 + c) * 128 + u8);
      }
#pragma unroll
      for (int i = 0; i < 2; i++) {
        int fi = t + 512 * i;
        rB[i] = make_uint4(0, 0, 0, 0);
        if (fi < 896) {
          int c = fi >> 3, u8 = (fi & 7) * 8;
          if (c < KPG)
            rB[i] = *(const uint4*)(w2t + (size_t)(g * KPG + c) * K_ASSIGN +
                                    k1 + u8);
        }
      }
    }

    f32x4 p[2][2];
    __builtin_amdgcn_s_setprio(1);
#pragma unroll
    for (int nt2 = 0; nt2 < 2; nt2++) {
      p[nt2][0] = (f32x4){0.f, 0.f, 0.f, 0.f};
      p[nt2][1] = (f32x4){0.f, 0.f, 0.f, 0.f};
      int nt = 2 * h + nt2;
#pragma unroll
      for (int kc = 0; kc < 4; kc++) {
        bf16x8 wf = *(bf16x8*)&w1c[(16 * nt + lr) * FA_WS + 32 * kc + 8 * lg];
        p[nt2][0] = __builtin_amdgcn_mfma_f32_16x16x32_bf16(wf, af[0][kc],
                                                            p[nt2][0], 0, 0, 0);
        p[nt2][1] = __builtin_amdgcn_mfma_f32_16x16x32_bf16(wf, af[1][kc],
                                                            p[nt2][1], 0, 0, 0);
      }
    }
    __builtin_amdgcn_s_setprio(0);
    unsigned q[2][2][2];
#pragma unroll
    for (int nt2 = 0; nt2 < 2; nt2++) {
      int kkb = k0 + 16 * (2 * h + nt2) + 4 * lg;
      float4 b1 = *(const float4*)(b1p + kkb);
#pragma unroll
      for (int ct = 0; ct < 2; ct++) {
        float r0 = frelu(p[nt2][ct][0] + b1.x);
        float r1 = frelu(p[nt2][ct][1] + b1.y);
        float r2 = frelu(p[nt2][ct][2] + b1.z);
        float r3 = frelu(p[nt2][ct][3] + b1.w);
        q[nt2][ct][0] = ((unsigned)f2bf(r1) << 16) | f2bf(r0);
        q[nt2][ct][1] = ((unsigned)f2bf(r3) << 16) | f2bf(r2);
      }
    }
    int sA = lr + 32 * (lg & 1);
    int sB = sA + 16;
    bool hi = (lg >= 2);
    FragU pa[2];
#pragma unroll
    for (int ct = 0; ct < 2; ct++) {
      unsigned a0 = (unsigned)__shfl((int)q[0][ct][0], sA, 64);
      unsigned b0 = (unsigned)__shfl((int)q[1][ct][0], sA, 64);
      unsigned a1 = (unsigned)__shfl((int)q[0][ct][1], sA, 64);
      unsigned b1u = (unsigned)__shfl((int)q[1][ct][1], sA, 64);
      unsigned a2 = (unsigned)__shfl((int)q[0][ct][0], sB, 64);
      unsigned b2u = (unsigned)__shfl((int)q[1][ct][0], sB, 64);
      unsigned a3 = (unsigned)__shfl((int)q[0][ct][1], sB, 64);
      unsigned b3u = (unsigned)__shfl((int)q[1][ct][1], sB, 64);
      pa[ct].u[0] = hi ? b0 : a0;
      pa[ct].u[1] = hi ? b1u : a1;
      pa[ct].u[2] = hi ? b2u : a2;
      pa[ct].u[3] = hi ? b3u : a3;
    }
    // prefetched chunk -> alternate buffers before phase-2 (drains under MFMA)
    if (pf) {
      unsigned short* w1n = (unsigned short*)(smem + (cur ^ 1) * FA_W1OFF);
      unsigned short* w2n =
          (unsigned short*)(smem + FA_W2BASE + (cur ^ 1) * FA_W2OFF);
#pragma unroll
      for (int i = 0; i < 2; i++) {
        int fi = t + 512 * i;
        int c = fi >> 4, u8 = (fi & 15) * 8;
        *(uint4*)&w1n[c * FA_WS + u8] = rA[i];
      }
#pragma unroll
      for (int i = 0; i < 2; i++) {
        int fi = t + 512 * i;
        if (fi < 896) {
          int c = fi >> 3, u8 = (fi & 7) * 8;
          *(uint4*)&w2n[c * FA_PS + u8] = rB[i];
        }
      }
    }
    __builtin_amdgcn_s_setprio(1);
#pragma unroll
    for (int ct2 = 0; ct2 < 7; ct2++) {
      bf16x8 wv = *(bf16x8*)&w2c[(16 * ct2 + lr) * FA_PS + 32 * h + 8 * lg];
      acc[ct2][0] = __builtin_amdgcn_mfma_f32_16x16x32_bf16(wv, pa[0].v,
                                                            acc[ct2][0], 0, 0, 0);
      acc[ct2][1] = __builtin_amdgcn_mfma_f32_16x16x32_bf16(wv, pa[1].v,
                                                            acc[ct2][1], 0, 0, 0);
    }
    __builtin_amdgcn_s_setprio(0);
    __syncthreads();
  }

  // cross-h reduction
  float* red = (float*)smem;
  if (h == 1) {
#pragma unroll
    for (int ct2 = 0; ct2 < 7; ct2++)
#pragma unroll
      for (int ct = 0; ct < 2; ct++)
        *(f32x4*)&red[((rh * 14 + ct2 * 2 + ct) * 64 + l) * 4] = acc[ct2][ct];
  }
  __syncthreads();
  if (h == 0) {
#pragma unroll
    for (int ct2 = 0; ct2 < 7; ct2++)
#pragma unroll
      for (int ct = 0; ct < 2; ct++)
        acc[ct2][ct] += *(f32x4*)&red[((rh * 14 + ct2 * 2 + ct) * 64 + l) * 4];

    // fused masked softmax
#pragma unroll
    for (int ct = 0; ct < 2; ct++) {
      int xrow = row0 + 32 * rh + 16 * ct + lr;
      float v[7][4];
      float m = 0.0f;
#pragma unroll
      for (int ct2 = 0; ct2 < 7; ct2++) {
        int col0 = 16 * ct2 + 4 * lg;
        if (col0 < KPG) {
          float4 b2 = *(const float4*)(b2p + g * KPG + col0);
          v[ct2][0] = frelu(acc[ct2][ct][0] + b2.x);
          v[ct2][1] = frelu(acc[ct2][ct][1] + b2.y);
          v[ct2][2] = frelu(acc[ct2][ct][2] + b2.z);
          v[ct2][3] = frelu(acc[ct2][ct][3] + b2.w);
          m = fmaxf(m, fmaxf(fmaxf(v[ct2][0], v[ct2][1]),
                             fmaxf(v[ct2][2], v[ct2][3])));
        }
      }
      m = fmaxf(m, __shfl_xor(m, 16, 64));
      m = fmaxf(m, __shfl_xor(m, 32, 64));
      float s = 0.0f;
#pragma unroll
      for (int ct2 = 0; ct2 < 7; ct2++) {
        int col0 = 16 * ct2 + 4 * lg;
        if (col0 < KPG) {
          v[ct2][0] = expf(v[ct2][0] - m);
          v[ct2][1] = expf(v[ct2][1] - m);
          v[ct2][2] = expf(v[ct2][2] - m);
          v[ct2][3] = expf(v[ct2][3] - m);
          s += (v[ct2][0] + v[ct2][1]) + (v[ct2][2] + v[ct2][3]);
        }
      }
      s += __shfl_xor(s, 16, 64);
      s += __shfl_xor(s, 32, 64);
      float denom = s + (float)(K_ASSIGN - KPG) * expf(-m);
      float scale = 1.0f / (s + 1e-13f * denom);
      if (xrow < NPG) {
#pragma unroll
        for (int ct2 = 0; ct2 < 7; ct2++) {
          int col0 = 16 * ct2 + 4 * lg;
          if (col0 < KPG) {
            ushort4 pk;
            pk.x = f2bf(v[ct2][0] * scale);
            pk.y = f2bf(v[ct2][1] * scale);
            pk.z = f2bf(v[ct2][2] * scale);
            pk.w = f2bf(v[ct2][3] * scale);
            *(ushort4*)(assign_bf + ((size_t)g * NPG + xrow) * KPG + col0) = pk;
          }
        }
      }
    }
  }
}

// ---------------------------------------------------------------------------
// tmp_bf[n] = sum_{e->n} assign_bf[src_e]. Standalone, high occupancy.
// ---------------------------------------------------------------------------
__global__ __launch_bounds__(256) void tmp_gather(
    const int* __restrict__ rowstart, const int* __restrict__ bucket,
    const unsigned short* __restrict__ assign_bf, unsigned short* __restrict__ tmp_bf) {
  int bid = (int)(blockIdx.x & 7) * 1000 + (int)(blockIdx.x >> 3);
  int n = bid * 4 + (threadIdx.x >> 6);
  int lane = threadIdx.x & 63;
  if (lane >= 50) return;
  int rs = rowstart[n], re = rowstart[n + 1];
  const unsigned* ab = (const unsigned*)assign_bf;
  float ax = 0.f, ay = 0.f;
  int e = rs;
  for (; e + 4 <= re; e += 4) {
    unsigned v0 = ab[(size_t)bucket[e] * 50 + lane];
    unsigned v1 = ab[(size_t)bucket[e + 1] * 50 + lane];
    unsigned v2 = ab[(size_t)bucket[e + 2] * 50 + lane];
    unsigned v3 = ab[(size_t)bucket[e + 3] * 50 + lane];
    ax += (bfLO(v0) + bfLO(v1)) + (bfLO(v2) + bfLO(v3));
    ay += (bfHI(v0) + bfHI(v1)) + (bfHI(v2) + bfHI(v3));
  }
  for (; e < re; e++) {
    unsigned v = ab[(size_t)bucket[e] * 50 + lane];
    ax += bfLO(v);
    ay += bfHI(v);
  }
  unsigned o = ((unsigned)f2bf(ay) << 16) | f2bf(ax);
  ((unsigned*)tmp_bf)[(size_t)n * 50 + lane] = o;
}

// ---------------------------------------------------------------------------
// pool (blocks 0..127) + adj (blocks 128..255), MFMA over K=n, PA_CHN=250.
// ---------------------------------------------------------------------------
#define PA_STR 72
#define PA_CHN 250
__global__ __launch_bounds__(256) void pool_adj_mfma(
    const unsigned short* __restrict__ assign_bf,
    const unsigned short* __restrict__ feat_bf,
    const unsigned short* __restrict__ tmp_bf,
    float* __restrict__ out_adj, float* __restrict__ out_hpool) {
  __shared__ __align__(16) unsigned short as[112 * PA_STR];
  __shared__ __align__(16) unsigned short bs[128 * PA_STR];
  bool is_pool = blockIdx.x < 128;
  int bb = is_pool ? blockIdx.x : blockIdx.x - 128;
  int g = bb >> 3, ch = bb & 7;
  int nbase = ch * PA_CHN;
  int lim = PA_CHN;  // 2000 = 8*250 exact
  int t = threadIdx.x;
  int w = t >> 6, l = t & 63, lr = l & 15, lg = l >> 4;
  const unsigned* au = (const unsigned*)assign_bf;
  const unsigned* fu = (const unsigned*)feat_bf;
  const unsigned* tu = (const unsigned*)tmp_bf;

  for (int i = t; i < 12 * PA_STR; i += 256) as[100 * PA_STR + i] = 0;
  for (int i = t; i < 28 * PA_STR; i += 256) bs[100 * PA_STR + i] = 0;

  f32x4 acc[7][2];
#pragma unroll
  for (int i = 0; i < 7; i++) {
    acc[i][0] = (f32x4){0.f, 0.f, 0.f, 0.f};
    acc[i][1] = (f32x4){0.f, 0.f, 0.f, 0.f};
  }

  for (int kt = 0; kt < 4; kt++) {  // 4 x 64 = 256 >= 250; tail zero-filled
    int nt0 = kt * 64;
    __syncthreads();
#pragma unroll
    for (int i = 0; i < 13; i++) {
      int idx = t + 256 * i;
      if (idx < 3200) {
        int r = idx / 50, cu = idx % 50;
        int nl = nt0 + r;
        unsigned v = 0;
        if (nl < lim) v = au[(size_t)(g * NPG + nbase + nl) * 50 + cu];
        as[(2 * cu) * PA_STR + r] = (unsigned short)(v & 0xFFFFu);
        as[(2 * cu + 1) * PA_STR + r] = (unsigned short)(v >> 16);
      }
    }
    if (is_pool) {
#pragma unroll
      for (int i = 0; i < 16; i++) {
        int idx = t + 256 * i;
        int r = idx >> 6, cu = idx & 63;
        int nl = nt0 + r;
        unsigned v = 0;
        if (nl < lim) v = fu[(size_t)(g * NPG + nbase + nl) * 64 + cu];
        bs[(2 * cu) * PA_STR + r] = (unsigned short)(v & 0xFFFFu);
        bs[(2 * cu + 1) * PA_STR + r] = (unsigned short)(v >> 16);
      }
    } else {
#pragma unroll
      for (int i = 0; i < 13; i++) {
        int idx = t + 256 * i;
        if (idx < 3200) {
          int r = idx / 50, cu = idx % 50;
          int nl = nt0 + r;
          unsigned v = 0;
          if (nl < lim) v = tu[(size_t)(g * NPG + nbase + nl) * 50 + cu];
          bs[(2 * cu) * PA_STR + r] = (unsigned short)(v & 0xFFFFu);
          bs[(2 * cu + 1) * PA_STR + r] = (unsigned short)(v >> 16);
        }
      }
    }
    __syncthreads();
#pragma unroll
    for (int kc = 0; kc < 2; kc++) {
      bf16x8 afr[7];
#pragma unroll
      for (int mt = 0; mt < 7; mt++)
        afr[mt] = *(bf16x8*)&as[(16 * mt + lr) * PA_STR + 32 * kc + 8 * lg];
#pragma unroll
      for (int nt2 = 0; nt2 < 2; nt2++) {
        int nt = 2 * w + nt2;
        bf16x8 bfr = *(bf16x8*)&bs[(16 * nt + lr) * PA_STR + 32 * kc + 8 * lg];
#pragma unroll
        for (int mt = 0; mt < 7; mt++)
          acc[mt][nt2] =
              __builtin_amdgcn_mfma_f32_16x16x32_bf16(afr[mt], bfr, acc[mt][nt2], 0, 0, 0);
      }
    }
  }

  if (is_pool) {
#pragma unroll
    for (int mt = 0; mt < 7; mt++)
#pragma unroll
      for (int nt2 = 0; nt2 < 2; nt2++) {
        int nt = 2 * w + nt2;
#pragma unroll
        for (int r = 0; r < 4; r++) {
          int m = 16 * mt + 4 * lg + r;
          if (m < KPG)
            atomicAdd(out_hpool + ((size_t)g * KPG + m) * 128 + 16 * nt + lr,
                      acc[mt][nt2][r]);
        }
      }
  } else {
#pragma unroll
    for (int mt = 0; mt < 7; mt++)
#pragma unroll
      for (int nt2 = 0; nt2 < 2; nt2++) {
        int nt = 2 * w + nt2;
        if (nt < 7) {
          int k2 = 16 * nt + lr;
          if (k2 < KPG) {
#pragma unroll
            for (int r = 0; r < 4; r++) {
              int m = 16 * mt + 4 * lg + r;
              if (m < KPG)
                atomicAdd(out_adj + ((size_t)g * KPG + m) * K_ASSIGN + g * KPG + k2,
                          acc[mt][nt2][r]);
            }
          }
        }
      }
  }
}

extern "C" void kernel_launch(void* const* d_in, const int* in_sizes, int n_in,
                              void* d_out, int out_size, void* d_ws,
                              size_t ws_size, hipStream_t stream) {
  (void)in_sizes; (void)n_in; (void)ws_size;
  const float* h   = (const float*)d_in[0];
  const int*   src = (const int*)d_in[1];
  const int*   dst = (const int*)d_in[2];
  const float* W1f = (const float*)d_in[3];
  const float* b1f = (const float*)d_in[4];
  const float* W2f = (const float*)d_in[5];
  const float* b2f = (const float*)d_in[6];
  const float* W1p = (const float*)d_in[7];
  const float* b1p = (const float*)d_in[8];
  const float* W2p = (const float*)d_in[9];
  const float* b2p = (const float*)d_in[10];

  float* out_adj   = (float*)d_out;
  float* out_hpool = out_adj + (size_t)K_ASSIGN * K_ASSIGN;

  char* ws = (char*)d_ws;
  int* deg_cnt  = (int*)(ws + 0);            //   128,000
  int* cursor   = (int*)(ws + 128000);       //   128,000
  int* rowstart = (int*)(ws + 256000);       //   128,032
  int* bucket   = (int*)(ws + 384032);       // 2,048,000
  unsigned short* h_bf      = (unsigned short*)(ws + 2432032);   // 8,192,000
  unsigned short* x_bf      = (unsigned short*)(ws + 10624032);  // 8,192,000
  unsigned short* feat_bf   = (unsigned short*)(ws + 18816032);  // 8,192,000
  unsigned short* assign_bf = (unsigned short*)(ws + 27008032);  // 6,400,000
  unsigned short* tmp_bf    = (unsigned short*)(ws + 33408032);  // 6,400,000
  unsigned short* w1f_t     = (unsigned short*)(ws + 39808032);  //    32,768
  unsigned short* w2f_t     = (unsigned short*)(ws + 39840800);  //    32,768
  unsigned short* w1p_t     = (unsigned short*)(ws + 39873568);  //   409,600
  unsigned short* w2p_t     = (unsigned short*)(ws + 40283168);  // 5,120,000

  hipMemsetAsync(deg_cnt, 0, 256000, stream);  // deg_cnt + cursor
  hipMemsetAsync(d_out, 0, (size_t)out_size * sizeof(float), stream);

  // K1: edge histogram + h->bf16 (critical path for scan/gin)
  hist_hbf<<<6000, 256, 0, stream>>>(dst, deg_cnt, h, h_bf);

  // CSR scan
  scan_counts<<<1, 1024, 0, stream>>>(deg_cnt, rowstart);

  // K3: edge_fill + weight transposes (transposes needed only by feat_assign)
  fill_transpose<<<4732, 256, 0, stream>>>(src, dst, rowstart, cursor, bucket,
                                           W1f, W2f, W1p, W2p,
                                           w1f_t, w2f_t, w1p_t, w2p_t);

  // aggregation (gather, XCD-swizzled) -> x in bf16
  gin_gather<<<N_NODES / 4, 256, 0, stream>>>(rowstart, bucket, h_bf, x_bf);

  // feat MLP + assign MLP + softmax, one launch (independent block ranges)
  feat_assign<<<256 + N_NODES / 128, 512, 0, stream>>>(
      x_bf, w1f_t, b1f, w2f_t, b2f, feat_bf,
      w1p_t, b1p, w2p_t, b2p, assign_bf);

  // adj @ assign via gather (standalone, high-occupancy)
  tmp_gather<<<N_NODES / 4, 256, 0, stream>>>(rowstart, bucket, assign_bf, tmp_bf);

  // outputs (MFMA, 250-row chunks -> half the atomic volume)
  pool_adj_mfma<<<256, 256, 0, stream>>>(assign_bf, feat_bf, tmp_bf,
                                         out_adj, out_hpool);
}